// Round 1
// baseline (1717.688 us; speedup 1.0000x reference)
//
#include <hip/hip_runtime.h>
#include <cmath>

#define S_LEN   2048
#define D_MODEL 2048
#define N3      6144
#define NH      16
#define HD      128

// ---------------------------------------------------------------------------
// fp32 GEMM with bias: C[M,N] = A[M,K] @ B[K,N] + bias[N]
// 128x128 block tile, BK=16, 8x8 micro-tile (split 4+4 rows/cols for
// conflict-free b128 LDS reads). ~4 FMA per LDS float => VALU/LDS balanced.
// ---------------------------------------------------------------------------
#define GBM 128
#define GBN 128
#define GBK 16

__global__ __launch_bounds__(256, 2) void sgemm_bias_kernel(
    const float* __restrict__ A, const float* __restrict__ B,
    const float* __restrict__ bias, float* __restrict__ C,
    int M, int N, int K)
{
    __shared__ float As[GBK][GBM];   // transposed A tile
    __shared__ float Bs[GBK][GBN];

    const int tid  = threadIdx.x;
    const int ty   = tid >> 4;       // 0..15
    const int tx   = tid & 15;       // 0..15
    const int brow = blockIdx.y * GBM;
    const int bcol = blockIdx.x * GBN;

    // loader mapping
    const int ar = tid >> 1;         // 0..127 (A tile row)
    const int ac = (tid & 1) * 8;    // 0 or 8 (A tile col)
    const int bk = tid >> 4;         // 0..15  (B tile row)
    const int bc = (tid & 15) * 8;   // 0..120 (B tile col)

    float acc[8][8];
#pragma unroll
    for (int i = 0; i < 8; ++i)
#pragma unroll
        for (int j = 0; j < 8; ++j) acc[i][j] = 0.f;

    for (int kk = 0; kk < K; kk += GBK) {
        __syncthreads();
        // stage A (transposed: As[k][m])
        float4 a0 = *(const float4*)(A + (size_t)(brow + ar) * K + kk + ac);
        float4 a1 = *(const float4*)(A + (size_t)(brow + ar) * K + kk + ac + 4);
        As[ac + 0][ar] = a0.x; As[ac + 1][ar] = a0.y;
        As[ac + 2][ar] = a0.z; As[ac + 3][ar] = a0.w;
        As[ac + 4][ar] = a1.x; As[ac + 5][ar] = a1.y;
        As[ac + 6][ar] = a1.z; As[ac + 7][ar] = a1.w;
        // stage B
        *(float4*)(&Bs[bk][bc])     = *(const float4*)(B + (size_t)(kk + bk) * N + bcol + bc);
        *(float4*)(&Bs[bk][bc + 4]) = *(const float4*)(B + (size_t)(kk + bk) * N + bcol + bc + 4);
        __syncthreads();

#pragma unroll
        for (int k = 0; k < GBK; ++k) {
            float4 va0 = *(const float4*)(&As[k][4 * ty]);
            float4 va1 = *(const float4*)(&As[k][64 + 4 * ty]);
            float4 vb0 = *(const float4*)(&Bs[k][4 * tx]);
            float4 vb1 = *(const float4*)(&Bs[k][64 + 4 * tx]);
            float av[8] = {va0.x, va0.y, va0.z, va0.w, va1.x, va1.y, va1.z, va1.w};
            float bv[8] = {vb0.x, vb0.y, vb0.z, vb0.w, vb1.x, vb1.y, vb1.z, vb1.w};
#pragma unroll
            for (int i = 0; i < 8; ++i)
#pragma unroll
                for (int j = 0; j < 8; ++j) acc[i][j] += av[i] * bv[j];
        }
    }

#pragma unroll
    for (int i = 0; i < 8; ++i) {
        const int row = brow + (i < 4 ? 4 * ty + i : 64 + 4 * ty + (i - 4));
#pragma unroll
        for (int jb = 0; jb < 2; ++jb) {
            const int col = bcol + jb * 64 + 4 * tx;
            float4 bb = *(const float4*)(bias + col);
            float4 o;
            o.x = acc[i][jb * 4 + 0] + bb.x;
            o.y = acc[i][jb * 4 + 1] + bb.y;
            o.z = acc[i][jb * 4 + 2] + bb.z;
            o.w = acc[i][jb * 4 + 3] + bb.w;
            *(float4*)(C + (size_t)row * N + col) = o;
        }
    }
}

// ---------------------------------------------------------------------------
// Dual-RoPE + split qkv [S,6144] into per-head Q/K/V [H][S][128].
// Head dim 128 = two 64-blocks (pos stream 1 / 2); within a block, pair
// (e, e+32) rotated by angle pos * 10000^(-e/32).
// One block per sequence position; 256 threads = 16 heads x 2 blocks x 8 f4.
// ---------------------------------------------------------------------------
__global__ __launch_bounds__(256) void rope_split_kernel(
    const float* __restrict__ qkv, const int* __restrict__ pid,
    float* __restrict__ Qr, float* __restrict__ Kr, float* __restrict__ Vr)
{
    const int s = blockIdx.x;
    const int t = threadIdx.x;
    const int h   = t >> 4;
    const int rem = t & 15;
    const int b   = rem >> 3;          // which 64-block (pos stream)
    const int e4  = (rem & 7) * 4;     // 0..28
    const size_t rowbase = (size_t)s * N3;
    const int cq = h * HD + b * 64 + e4;

    float4 q1 = *(const float4*)(qkv + rowbase + cq);
    float4 q2 = *(const float4*)(qkv + rowbase + cq + 32);
    float4 k1 = *(const float4*)(qkv + rowbase + D_MODEL + cq);
    float4 k2 = *(const float4*)(qkv + rowbase + D_MODEL + cq + 32);

    const float pos = (float)((b == 0) ? pid[s] : pid[S_LEN + s]);

    float qa[4] = {q1.x, q1.y, q1.z, q1.w};
    float qb[4] = {q2.x, q2.y, q2.z, q2.w};
    float ka[4] = {k1.x, k1.y, k1.z, k1.w};
    float kb[4] = {k2.x, k2.y, k2.z, k2.w};
    float qo1[4], qo2[4], ko1[4], ko2[4];

#pragma unroll
    for (int u = 0; u < 4; ++u) {
        const float j    = (float)(e4 + u);
        const float invf = powf(10000.f, -j * (1.f / 32.f));
        const float ang  = pos * invf;
        float sn, cs;
        sincosf(ang, &sn, &cs);
        qo1[u] = qa[u] * cs - qb[u] * sn;
        qo2[u] = qb[u] * cs + qa[u] * sn;
        ko1[u] = ka[u] * cs - kb[u] * sn;
        ko2[u] = kb[u] * cs + ka[u] * sn;
    }

    float* qdst = Qr + ((size_t)h * S_LEN + s) * HD + b * 64 + e4;
    float* kdst = Kr + ((size_t)h * S_LEN + s) * HD + b * 64 + e4;
    *(float4*)(qdst)      = make_float4(qo1[0], qo1[1], qo1[2], qo1[3]);
    *(float4*)(qdst + 32) = make_float4(qo2[0], qo2[1], qo2[2], qo2[3]);
    *(float4*)(kdst)      = make_float4(ko1[0], ko1[1], ko1[2], ko1[3]);
    *(float4*)(kdst + 32) = make_float4(ko2[0], ko2[1], ko2[2], ko2[3]);

    // V: straight copy into [H][S][128]
    const int vcol = t * 8;
    const int vh   = vcol >> 7;
    const int vd   = vcol & 127;
    float4 v0 = *(const float4*)(qkv + rowbase + 2 * D_MODEL + vcol);
    float4 v1 = *(const float4*)(qkv + rowbase + 2 * D_MODEL + vcol + 4);
    float* vdst = Vr + ((size_t)vh * S_LEN + s) * HD + vd;
    *(float4*)(vdst)     = v0;
    *(float4*)(vdst + 4) = v1;
}

// ---------------------------------------------------------------------------
// Flash attention fp32, unscaled, no mask. One block = (head, 64-row q tile).
// Q/K/V tiles [64][128] in LDS with XOR granule swizzle (g ^= (row>>2)&7) so
// staging writes and per-row float4 reads are <=2-way bank aliased (free).
// Online softmax stats reduced over the 16 tx lanes via shfl_xor.
// LDS = 3*32KB + P tile 17KB = 113KB (dynamic).
// ---------------------------------------------------------------------------
#define QT 64
#define KT 64
#define PS_LD 68

__global__ __launch_bounds__(256, 1) void attn_fp32_kernel(
    const float* __restrict__ Q, const float* __restrict__ K,
    const float* __restrict__ V, float* __restrict__ O)
{
    extern __shared__ float lds[];
    float* Qs = lds;                  // QT*HD
    float* Ks = Qs + QT * HD;         // KT*HD
    float* Vs = Ks + KT * HD;         // KT*HD
    float* Ps = Vs + KT * HD;         // QT*PS_LD

    const int h   = blockIdx.y;
    const int qt  = blockIdx.x;
    const int tid = threadIdx.x;
    const int ty  = tid >> 4;
    const int tx  = tid & 15;

    const float* Qh = Q + (size_t)h * S_LEN * HD;
    const float* Kh = K + (size_t)h * S_LEN * HD;
    const float* Vh = V + (size_t)h * S_LEN * HD;

    // stage Q tile (swizzled)
    {
        const int g  = tid & 31;
        const int rb = (tid >> 5) * 8;
#pragma unroll
        for (int j = 0; j < 8; ++j) {
            const int r = rb + j;
            float4 v = *(const float4*)(Qh + (size_t)(qt * QT + r) * HD + g * 4);
            *(float4*)(Qs + r * HD + ((g ^ ((r >> 2) & 7)) << 2)) = v;
        }
    }

    float mrun[4], lrun[4], acc[4][8];
#pragma unroll
    for (int i = 0; i < 4; ++i) {
        mrun[i] = -INFINITY;
        lrun[i] = 0.f;
#pragma unroll
        for (int c = 0; c < 8; ++c) acc[i][c] = 0.f;
    }

    const int sq = ty & 7;
    const int sk = tx & 7;

    for (int kt = 0; kt < S_LEN / KT; ++kt) {
        __syncthreads();
        // stage K, V tiles (swizzled)
        {
            const int g  = tid & 31;
            const int rb = (tid >> 5) * 8;
            const float* Kg = Kh + (size_t)(kt * KT) * HD;
            const float* Vg = Vh + (size_t)(kt * KT) * HD;
#pragma unroll
            for (int j = 0; j < 8; ++j) {
                const int r  = rb + j;
                const int gs = ((g ^ ((r >> 2) & 7)) << 2);
                *(float4*)(Ks + r * HD + gs) = *(const float4*)(Kg + (size_t)r * HD + g * 4);
                *(float4*)(Vs + r * HD + gs) = *(const float4*)(Vg + (size_t)r * HD + g * 4);
            }
        }
        __syncthreads();

        // phase 1: logits tile s = Q K^T (4q x 4k per thread)
        float sreg[4][4];
#pragma unroll
        for (int i = 0; i < 4; ++i)
#pragma unroll
            for (int j = 0; j < 4; ++j) sreg[i][j] = 0.f;

        for (int gd = 0; gd < 32; ++gd) {
            const int cq = ((gd ^ sq) << 2);
            const int ck = ((gd ^ sk) << 2);
            float4 q4[4], k4[4];
#pragma unroll
            for (int i = 0; i < 4; ++i) q4[i] = *(const float4*)(Qs + (4 * ty + i) * HD + cq);
#pragma unroll
            for (int j = 0; j < 4; ++j) k4[j] = *(const float4*)(Ks + (4 * tx + j) * HD + ck);
#pragma unroll
            for (int i = 0; i < 4; ++i)
#pragma unroll
                for (int j = 0; j < 4; ++j)
                    sreg[i][j] += q4[i].x * k4[j].x + q4[i].y * k4[j].y +
                                  q4[i].z * k4[j].z + q4[i].w * k4[j].w;
        }

        // online softmax update
        float pv[4][4];
#pragma unroll
        for (int i = 0; i < 4; ++i) {
            float tm = fmaxf(fmaxf(sreg[i][0], sreg[i][1]), fmaxf(sreg[i][2], sreg[i][3]));
            tm = fmaxf(tm, __shfl_xor(tm, 1));
            tm = fmaxf(tm, __shfl_xor(tm, 2));
            tm = fmaxf(tm, __shfl_xor(tm, 4));
            tm = fmaxf(tm, __shfl_xor(tm, 8));
            const float mnew  = fmaxf(mrun[i], tm);
            const float scale = __expf(mrun[i] - mnew);
            float psum = 0.f;
#pragma unroll
            for (int j = 0; j < 4; ++j) {
                pv[i][j] = __expf(sreg[i][j] - mnew);
                psum += pv[i][j];
            }
            psum += __shfl_xor(psum, 1);
            psum += __shfl_xor(psum, 2);
            psum += __shfl_xor(psum, 4);
            psum += __shfl_xor(psum, 8);
            lrun[i] = lrun[i] * scale + psum;
            mrun[i] = mnew;
#pragma unroll
            for (int c = 0; c < 8; ++c) acc[i][c] *= scale;
        }
#pragma unroll
        for (int i = 0; i < 4; ++i)
            *(float4*)(Ps + (4 * ty + i) * PS_LD + 4 * tx) =
                make_float4(pv[i][0], pv[i][1], pv[i][2], pv[i][3]);
        __syncthreads();

        // phase 2: acc += P * V  (4q x 8d per thread)
        for (int k4i = 0; k4i < KT; k4i += 4) {
            float4 p4[4];
#pragma unroll
            for (int i = 0; i < 4; ++i)
                p4[i] = *(const float4*)(Ps + (4 * ty + i) * PS_LD + k4i);
#pragma unroll
            for (int u = 0; u < 4; ++u) {
                const int kj = k4i + u;
                const int sv = (kj >> 2) & 7;
                const float4 v0 = *(const float4*)(Vs + kj * HD + ((tx ^ sv) << 2));
                const float4 v1 = *(const float4*)(Vs + kj * HD + (((16 + tx) ^ sv) << 2));
#pragma unroll
                for (int i = 0; i < 4; ++i) {
                    const float p = (u == 0) ? p4[i].x : (u == 1) ? p4[i].y
                                  : (u == 2) ? p4[i].z : p4[i].w;
                    acc[i][0] += p * v0.x; acc[i][1] += p * v0.y;
                    acc[i][2] += p * v0.z; acc[i][3] += p * v0.w;
                    acc[i][4] += p * v1.x; acc[i][5] += p * v1.y;
                    acc[i][6] += p * v1.z; acc[i][7] += p * v1.w;
                }
            }
        }
    }

    // epilogue: normalize, write O[s][h*128 + c]
#pragma unroll
    for (int i = 0; i < 4; ++i) {
        const float inv = 1.f / lrun[i];
        const size_t row = (size_t)(qt * QT + 4 * ty + i);
        float4 o0 = make_float4(acc[i][0] * inv, acc[i][1] * inv, acc[i][2] * inv, acc[i][3] * inv);
        float4 o1 = make_float4(acc[i][4] * inv, acc[i][5] * inv, acc[i][6] * inv, acc[i][7] * inv);
        *(float4*)(O + row * D_MODEL + h * HD + 4 * tx)      = o0;
        *(float4*)(O + row * D_MODEL + h * HD + 64 + 4 * tx) = o1;
    }
}

// ---------------------------------------------------------------------------
// launch
// ---------------------------------------------------------------------------
extern "C" void kernel_launch(void* const* d_in, const int* in_sizes, int n_in,
                              void* d_out, int out_size, void* d_ws, size_t ws_size,
                              hipStream_t stream)
{
    const float* x    = (const float*)d_in[0];
    const float* Wqkv = (const float*)d_in[1];
    const float* bqkv = (const float*)d_in[2];
    const float* Wo   = (const float*)d_in[3];
    const float* bo   = (const float*)d_in[4];
    const int*   pid  = (const int*)d_in[5];
    float* out = (float*)d_out;
    float* ws  = (float*)d_ws;

    // workspace layout (floats):
    // [0, 12582912)              qkv  [S][6144]   (48 MB) -- dead after rope
    // [12582912, 16777216+...)   Qr/Kr/Vr [H][S][128] (16 MB each)
    // attention output aliases qkv region ([S][2048], 16 MB)
    float* qkv  = ws;
    float* Qr   = ws + (size_t)12582912;
    float* Kr   = Qr + (size_t)4194304;
    float* Vr   = Kr + (size_t)4194304;
    float* attn = ws;

    // 1) fused QKV projection
    sgemm_bias_kernel<<<dim3(N3 / GBN, S_LEN / GBM), 256, 0, stream>>>(
        x, Wqkv, bqkv, qkv, S_LEN, N3, D_MODEL);

    // 2) dual RoPE + per-head split
    rope_split_kernel<<<dim3(S_LEN), 256, 0, stream>>>(qkv, pid, Qr, Kr, Vr);

    // 3) flash attention
    const int attn_lds = (QT * HD + KT * HD + KT * HD + QT * PS_LD) * (int)sizeof(float);
    hipFuncSetAttribute(reinterpret_cast<const void*>(attn_fp32_kernel),
                        hipFuncAttributeMaxDynamicSharedMemorySize, attn_lds);
    attn_fp32_kernel<<<dim3(S_LEN / QT, NH), 256, attn_lds, stream>>>(Qr, Kr, Vr, attn);

    // 4) output projection
    sgemm_bias_kernel<<<dim3(D_MODEL / GBN, S_LEN / GBM), 256, 0, stream>>>(
        attn, Wo, bo, out, S_LEN, D_MODEL, D_MODEL);
}

// Round 2
// 514.802 us; speedup vs baseline: 3.3366x; 3.3366x over previous
//
#include <hip/hip_runtime.h>
#include <cmath>

typedef __attribute__((ext_vector_type(8))) short short8;
typedef __attribute__((ext_vector_type(4))) float f32x4;

#define S_LEN 2048
#define DM    2048

__device__ __forceinline__ unsigned short f2bf(float f) {
    unsigned u = __float_as_uint(f);
    u = (u + 0x7fffu + ((u >> 16) & 1u)) >> 16;
    return (unsigned short)u;
}
__device__ __forceinline__ float bf2f(unsigned short h) {
    return __uint_as_float(((unsigned)h) << 16);
}
__device__ __forceinline__ void gload16(const void* g, void* l) {
    __builtin_amdgcn_global_load_lds(
        (const __attribute__((address_space(1))) unsigned*)g,
        (__attribute__((address_space(3))) unsigned*)l, 16, 0, 0);
}

// ---------------------------------------------------------------------------
// x [2048][2048] fp32 -> x2 [2048][4096] bf16 ([hi(2048) | lo(2048)])
// ---------------------------------------------------------------------------
__global__ __launch_bounds__(256) void conv_x_kernel(
    const float* __restrict__ x, unsigned short* __restrict__ x2)
{
    const int idx = blockIdx.x * 256 + threadIdx.x;  // 4 floats each
    const int r = idx >> 9;
    const int c = (idx & 511) << 2;
    float4 v = *(const float4*)(x + (size_t)r * 2048 + c);
    unsigned short h0 = f2bf(v.x), h1 = f2bf(v.y), h2 = f2bf(v.z), h3 = f2bf(v.w);
    ushort4 hv = make_ushort4(h0, h1, h2, h3);
    ushort4 lv = make_ushort4(f2bf(v.x - bf2f(h0)), f2bf(v.y - bf2f(h1)),
                              f2bf(v.z - bf2f(h2)), f2bf(v.w - bf2f(h3)));
    *(ushort4*)(x2 + (size_t)r * 4096 + c) = hv;
    *(ushort4*)(x2 + (size_t)r * 4096 + 2048 + c) = lv;
}

// ---------------------------------------------------------------------------
// W fp32 [2048][N] -> Wt [N][4096] bf16, Wt[n][k]=hi(W[k][n]), [n][2048+k]=lo
// 64x64 LDS tile transpose.
// ---------------------------------------------------------------------------
__global__ __launch_bounds__(256) void tw_kernel(
    const float* __restrict__ W, unsigned short* __restrict__ Wt, int N)
{
    __shared__ float T[64][65];
    const int t = threadIdx.x;
    const int bx = blockIdx.x;   // n block
    const int by = blockIdx.y;   // k block (32)
    {
        const int c = (t & 15) * 4;
        const int r0 = t >> 4;
#pragma unroll
        for (int i = 0; i < 4; ++i) {
            const int r = r0 + i * 16;
            float4 v = *(const float4*)(W + (size_t)(by * 64 + r) * N + bx * 64 + c);
            T[r][c] = v.x; T[r][c + 1] = v.y; T[r][c + 2] = v.z; T[r][c + 3] = v.w;
        }
    }
    __syncthreads();
    const int n = t >> 2;
    const int kq = (t & 3) * 16;
    unsigned hp[8], lp[8];
#pragma unroll
    for (int j = 0; j < 16; j += 2) {
        float f0 = T[kq + j][n], f1 = T[kq + j + 1][n];
        unsigned short a0 = f2bf(f0), a1 = f2bf(f1);
        unsigned short b0 = f2bf(f0 - bf2f(a0)), b1 = f2bf(f1 - bf2f(a1));
        hp[j >> 1] = (unsigned)a0 | ((unsigned)a1 << 16);
        lp[j >> 1] = (unsigned)b0 | ((unsigned)b1 << 16);
    }
    unsigned short* dst = Wt + (size_t)(bx * 64 + n) * 4096 + by * 64 + kq;
    *(uint4*)(dst)            = make_uint4(hp[0], hp[1], hp[2], hp[3]);
    *(uint4*)(dst + 8)        = make_uint4(hp[4], hp[5], hp[6], hp[7]);
    *(uint4*)(dst + 2048)     = make_uint4(lp[0], lp[1], lp[2], lp[3]);
    *(uint4*)(dst + 2048 + 8) = make_uint4(lp[4], lp[5], lp[6], lp[7]);
}

// ---------------------------------------------------------------------------
// split-bf16 GEMM: C[M][N] = A@W + bias via logical K' = 3*2048.
// A2 [M][4096] ([Ahi|Alo]); B2t [N][4096] ([Bhi|Blo], K-major).
// term 0: Ahi*Bhi, 1: Ahi*Blo, 2: Alo*Bhi.
// 128x128 tile, BK=64, 4 waves (2x2 of 64x64), global_load_lds w=16 with
// pre-swizzled source; (r&7) XOR granule swizzle -> conflict-free b128 reads.
// ---------------------------------------------------------------------------
__global__ __launch_bounds__(256, 2) void gemm_split_kernel(
    const unsigned short* __restrict__ A2, const unsigned short* __restrict__ B2t,
    const float* __restrict__ bias, float* __restrict__ C, int N, int nbx, int nwg)
{
    __shared__ unsigned short As[128 * 64];
    __shared__ unsigned short Bs[128 * 64];
    const int wk = ((blockIdx.x & 7) * (nwg >> 3)) + (blockIdx.x >> 3);  // XCD swizzle
    const int bx = wk % nbx, by = wk / nbx;
    const int tid = threadIdx.x;
    const int lane = tid & 63, wv = tid >> 6;
    const int lr = lane & 15, hi8 = lane >> 4, kx = lane & 7;
    const int wm = wv >> 1, wn = wv & 1;

    f32x4 acc[4][4];
#pragma unroll
    for (int i = 0; i < 4; ++i)
#pragma unroll
        for (int j = 0; j < 4; ++j) acc[i][j] = f32x4{0.f, 0.f, 0.f, 0.f};

    int ldso[4]; size_t goff[4];
#pragma unroll
    for (int i = 0; i < 4; ++i) {
        const int gr = i * 256 + tid;        // 16B granule id (1024 per tile)
        const int rr = gr >> 3, ss = gr & 7;
        const int gg = ss ^ (rr & 7);        // inverse swizzle on source
        ldso[i] = gr * 8;
        goff[i] = (size_t)rr * 4096 + gg * 8;
    }

    const unsigned short* Abase = A2 + (size_t)by * 128 * 4096;
    const unsigned short* Bbase = B2t + (size_t)bx * 128 * 4096;

#pragma unroll
    for (int term = 0; term < 3; ++term) {
        const unsigned short* Ag = Abase + (term == 2 ? 2048 : 0);
        const unsigned short* Bg = Bbase + (term == 1 ? 2048 : 0);
        for (int s32 = 0; s32 < 32; ++s32) {
#pragma unroll
            for (int i = 0; i < 4; ++i) gload16(Ag + goff[i], &As[ldso[i]]);
#pragma unroll
            for (int i = 0; i < 4; ++i) gload16(Bg + goff[i], &Bs[ldso[i]]);
            __syncthreads();   // compiler drains vmcnt here -> tiles ready
#pragma unroll
            for (int kc = 0; kc < 2; ++kc) {
                const int slot8 = ((kc * 4 + hi8) ^ kx) * 8;
                short8 aF[4], bF[4];
#pragma unroll
                for (int mt = 0; mt < 4; ++mt)
                    aF[mt] = *(const short8*)&As[(wm * 64 + mt * 16 + lr) * 64 + slot8];
#pragma unroll
                for (int nt = 0; nt < 4; ++nt)
                    bF[nt] = *(const short8*)&Bs[(wn * 64 + nt * 16 + lr) * 64 + slot8];
#pragma unroll
                for (int mt = 0; mt < 4; ++mt)
#pragma unroll
                    for (int nt = 0; nt < 4; ++nt)
                        acc[mt][nt] = __builtin_amdgcn_mfma_f32_16x16x32_bf16(
                            aF[mt], bF[nt], acc[mt][nt], 0, 0, 0);
            }
            __syncthreads();   // all reads done before next overwrite
            Ag += 64; Bg += 64;
        }
    }

#pragma unroll
    for (int nt = 0; nt < 4; ++nt) {
        const int col = bx * 128 + wn * 64 + nt * 16 + lr;
        const float bv = bias[col];
#pragma unroll
        for (int mt = 0; mt < 4; ++mt)
#pragma unroll
            for (int r = 0; r < 4; ++r) {
                const int row = by * 128 + wm * 64 + mt * 16 + hi8 * 4 + r;
                C[(size_t)row * N + col] = acc[mt][nt][r] + bv;
            }
    }
}

// ---------------------------------------------------------------------------
// Dual RoPE: qkv fp32 [S][6144] -> Q2/K2 [H][S][256] bf16 ([hi(128)|lo(128)])
// ---------------------------------------------------------------------------
__global__ __launch_bounds__(256) void rope_kernel(
    const float* __restrict__ qkv, const int* __restrict__ pid,
    unsigned short* __restrict__ Q2, unsigned short* __restrict__ K2)
{
    const int s = blockIdx.x, t = threadIdx.x;
    const int h = t >> 4, rem = t & 15, b = rem >> 3, e4 = (rem & 7) * 4;
    const size_t rb = (size_t)s * 6144;
    const int cq = h * 128 + b * 64 + e4;

    float4 q1 = *(const float4*)(qkv + rb + cq);
    float4 q2v = *(const float4*)(qkv + rb + cq + 32);
    float4 k1 = *(const float4*)(qkv + rb + 2048 + cq);
    float4 k2v = *(const float4*)(qkv + rb + 2048 + cq + 32);
    const float pos = (float)((b == 0) ? pid[s] : pid[2048 + s]);

    float qa[4] = {q1.x, q1.y, q1.z, q1.w};
    float qb[4] = {q2v.x, q2v.y, q2v.z, q2v.w};
    float ka[4] = {k1.x, k1.y, k1.z, k1.w};
    float kb[4] = {k2v.x, k2v.y, k2v.z, k2v.w};
    float qo1[4], qo2[4], ko1[4], ko2[4];
#pragma unroll
    for (int u = 0; u < 4; ++u) {
        const float j = (float)(e4 + u);
        const float invf = powf(10000.f, -j * (1.f / 32.f));
        const float ang = pos * invf;
        float sn, cs;
        sincosf(ang, &sn, &cs);
        qo1[u] = qa[u] * cs - qb[u] * sn;
        qo2[u] = qb[u] * cs + qa[u] * sn;
        ko1[u] = ka[u] * cs - kb[u] * sn;
        ko2[u] = kb[u] * cs + ka[u] * sn;
    }

    unsigned short* qd = Q2 + ((size_t)h * 2048 + s) * 256 + b * 64 + e4;
    unsigned short* kd = K2 + ((size_t)h * 2048 + s) * 256 + b * 64 + e4;
    ushort4 t4;
#pragma unroll
    for (int pass = 0; pass < 2; ++pass) {
        float* v1 = pass ? ko1 : qo1;
        float* v2 = pass ? ko2 : qo2;
        unsigned short* d = pass ? kd : qd;
        unsigned short hh[8], ll[8];
#pragma unroll
        for (int u = 0; u < 4; ++u) {
            hh[u] = f2bf(v1[u]);     ll[u] = f2bf(v1[u] - bf2f(hh[u]));
            hh[4 + u] = f2bf(v2[u]); ll[4 + u] = f2bf(v2[u] - bf2f(hh[4 + u]));
        }
        t4 = make_ushort4(hh[0], hh[1], hh[2], hh[3]); *(ushort4*)(d) = t4;
        t4 = make_ushort4(hh[4], hh[5], hh[6], hh[7]); *(ushort4*)(d + 32) = t4;
        t4 = make_ushort4(ll[0], ll[1], ll[2], ll[3]); *(ushort4*)(d + 128) = t4;
        t4 = make_ushort4(ll[4], ll[5], ll[6], ll[7]); *(ushort4*)(d + 160) = t4;
    }
}

// ---------------------------------------------------------------------------
// V transpose: qkv cols [4096,6144) fp32 -> Vt [H][128][S] bf16
// ---------------------------------------------------------------------------
__global__ __launch_bounds__(256) void tv_kernel(
    const float* __restrict__ qkv, unsigned short* __restrict__ Vt)
{
    __shared__ float T[64][65];
    const int t = threadIdx.x;
    const int bs = blockIdx.x;   // s block (32)
    const int bc = blockIdx.y;   // v-col block (32)
    {
        const int c = (t & 15) * 4;
        const int r0 = t >> 4;
#pragma unroll
        for (int i = 0; i < 4; ++i) {
            const int r = r0 + i * 16;
            float4 v = *(const float4*)(qkv + (size_t)(bs * 64 + r) * 6144 + 4096 + bc * 64 + c);
            T[r][c] = v.x; T[r][c + 1] = v.y; T[r][c + 2] = v.z; T[r][c + 3] = v.w;
        }
    }
    __syncthreads();
    const int d = t >> 2;
    const int sq = (t & 3) * 16;
    const int gcol = bc * 64 + d;
    const int h = gcol >> 7, dd = gcol & 127;
    unsigned hp[8];
#pragma unroll
    for (int j = 0; j < 16; j += 2) {
        hp[j >> 1] = (unsigned)f2bf(T[sq + j][d]) | ((unsigned)f2bf(T[sq + j + 1][d]) << 16);
    }
    unsigned short* dst = Vt + ((size_t)h * 128 + dd) * 2048 + bs * 64 + sq;
    *(uint4*)(dst)     = make_uint4(hp[0], hp[1], hp[2], hp[3]);
    *(uint4*)(dst + 8) = make_uint4(hp[4], hp[5], hp[6], hp[7]);
}

// ---------------------------------------------------------------------------
// MFMA flash attention. Block = (head, 64-q-tile), 4 waves (16 q rows each).
// QK^T split-bf16 (3 terms over [hi|lo]); softmax fp32; PV plain bf16.
// Q fragments hoisted in registers. Ks [64][256], Vs [128][64] swizzled LDS
// staged via pre-swizzled global_load_lds. Out written as [hi|lo] for GEMM2.
// ---------------------------------------------------------------------------
__global__ __launch_bounds__(256, 2) void attn_kernel(
    const unsigned short* __restrict__ Q2, const unsigned short* __restrict__ K2,
    const unsigned short* __restrict__ Vt, unsigned short* __restrict__ A2)
{
    __shared__ unsigned short Ks[64 * 256];
    __shared__ unsigned short Vs[128 * 64];
    __shared__ unsigned short Ps[4 * 16 * 72];

    const int bid = blockIdx.x;
    const int tq = bid >> 3;
    const int h = (tq & 1) | ((bid & 7) << 1);   // 2 heads per XCD -> L2-resident K/V
    const int qt = tq >> 1;
    const int tid = threadIdx.x;
    const int w = tid >> 6, lane = tid & 63;
    const int lr = lane & 15, hi8 = lane >> 4, kx = lane & 7;

    short8 qf[8];
    {
        const unsigned short* Qr = Q2 + ((size_t)h * 2048 + qt * 64 + w * 16 + lr) * 256;
#pragma unroll
        for (int c = 0; c < 4; ++c) {
            qf[c]     = *(const short8*)(Qr + c * 32 + hi8 * 8);        // hi
            qf[4 + c] = *(const short8*)(Qr + 128 + c * 32 + hi8 * 8);  // lo
        }
    }

    f32x4 acco[8];
    float mrun[4], lrun[4];
#pragma unroll
    for (int i = 0; i < 8; ++i) acco[i] = f32x4{0.f, 0.f, 0.f, 0.f};
#pragma unroll
    for (int r = 0; r < 4; ++r) { mrun[r] = -INFINITY; lrun[r] = 0.f; }

    int kl[8]; size_t kg[8];
#pragma unroll
    for (int i = 0; i < 8; ++i) {
        const int gr = i * 256 + tid;
        const int rr = gr >> 5, ss = gr & 31;
        const int gg = (ss & 24) | ((ss & 7) ^ (rr & 7));
        kl[i] = gr * 8;
        kg[i] = (size_t)rr * 256 + gg * 8;
    }
    int vl[4]; size_t vg[4];
#pragma unroll
    for (int i = 0; i < 4; ++i) {
        const int gr = i * 256 + tid;
        const int rr = gr >> 3, ss = gr & 7;
        const int gg = ss ^ (rr & 7);
        vl[i] = gr * 8;
        vg[i] = (size_t)rr * 2048 + gg * 8;
    }

    const unsigned short* Kh = K2 + (size_t)h * 2048 * 256;
    const unsigned short* Vh = Vt + (size_t)h * 128 * 2048;
    unsigned short* Pw = Ps + w * 16 * 72;

    for (int kt = 0; kt < 32; ++kt) {
        const unsigned short* Kg = Kh + (size_t)kt * 64 * 256;
        const unsigned short* Vg = Vh + kt * 64;
#pragma unroll
        for (int i = 0; i < 8; ++i) gload16(Kg + kg[i], &Ks[kl[i]]);
#pragma unroll
        for (int i = 0; i < 4; ++i) gload16(Vg + vg[i], &Vs[vl[i]]);
        __syncthreads();

        // QK^T (split: Qhi*Khi + Qhi*Klo + Qlo*Khi)
        f32x4 sacc[4];
#pragma unroll
        for (int ct = 0; ct < 4; ++ct) {
            f32x4 a = f32x4{0.f, 0.f, 0.f, 0.f};
            const int rowb = (ct * 16 + lr) * 256;
#pragma unroll
            for (int t3 = 0; t3 < 3; ++t3) {
                const int qs = (t3 == 2) ? 4 : 0;
                const int kb8 = (t3 == 1) ? 16 : 0;
#pragma unroll
                for (int c = 0; c < 4; ++c) {
                    const int g = c * 4 + hi8;
                    const int slot = (kb8 + (g & 8)) | ((g & 7) ^ kx);
                    short8 kf = *(const short8*)&Ks[rowb + slot * 8];
                    a = __builtin_amdgcn_mfma_f32_16x16x32_bf16(qf[qs + c], kf, a, 0, 0, 0);
                }
            }
            sacc[ct] = a;
        }

        // online softmax over rows hi8*4+r
        float scl[4];
#pragma unroll
        for (int r = 0; r < 4; ++r) {
            float tm = fmaxf(fmaxf(sacc[0][r], sacc[1][r]), fmaxf(sacc[2][r], sacc[3][r]));
            tm = fmaxf(tm, __shfl_xor(tm, 1));
            tm = fmaxf(tm, __shfl_xor(tm, 2));
            tm = fmaxf(tm, __shfl_xor(tm, 4));
            tm = fmaxf(tm, __shfl_xor(tm, 8));
            const float mnew = fmaxf(mrun[r], tm);
            const float sc = __expf(mrun[r] - mnew);
            float pv[4], ps = 0.f;
#pragma unroll
            for (int ct = 0; ct < 4; ++ct) { pv[ct] = __expf(sacc[ct][r] - mnew); ps += pv[ct]; }
            ps += __shfl_xor(ps, 1); ps += __shfl_xor(ps, 2);
            ps += __shfl_xor(ps, 4); ps += __shfl_xor(ps, 8);
            lrun[r] = lrun[r] * sc + ps;
            mrun[r] = mnew;
            scl[r] = sc;
#pragma unroll
            for (int ct = 0; ct < 4; ++ct)
                Pw[(hi8 * 4 + r) * 72 + ct * 16 + lr] = f2bf(pv[ct]);
        }
#pragma unroll
        for (int dt = 0; dt < 8; ++dt)
#pragma unroll
            for (int r = 0; r < 4; ++r) acco[dt][r] *= scl[r];

        // PV (plain bf16)
        short8 pf0 = *(const short8*)&Pw[lr * 72 + hi8 * 8];
        short8 pf1 = *(const short8*)&Pw[lr * 72 + 32 + hi8 * 8];
#pragma unroll
        for (int dt = 0; dt < 8; ++dt) {
            const int rowb = (dt * 16 + lr) * 64;
            short8 vf0 = *(const short8*)&Vs[rowb + ((0 + hi8) ^ kx) * 8];
            short8 vf1 = *(const short8*)&Vs[rowb + ((4 + hi8) ^ kx) * 8];
            acco[dt] = __builtin_amdgcn_mfma_f32_16x16x32_bf16(pf0, vf0, acco[dt], 0, 0, 0);
            acco[dt] = __builtin_amdgcn_mfma_f32_16x16x32_bf16(pf1, vf1, acco[dt], 0, 0, 0);
        }
        __syncthreads();
    }

    // epilogue: normalize, write [hi|lo] row for GEMM2
#pragma unroll
    for (int dt = 0; dt < 8; ++dt) {
        const int n = h * 128 + dt * 16 + lr;
#pragma unroll
        for (int r = 0; r < 4; ++r) {
            const int srow = qt * 64 + w * 16 + hi8 * 4 + r;
            const float o = acco[dt][r] / lrun[r];
            const unsigned short hb = f2bf(o);
            A2[(size_t)srow * 4096 + n] = hb;
            A2[(size_t)srow * 4096 + 2048 + n] = f2bf(o - bf2f(hb));
        }
    }
}

// ---------------------------------------------------------------------------
// launch
// ---------------------------------------------------------------------------
extern "C" void kernel_launch(void* const* d_in, const int* in_sizes, int n_in,
                              void* d_out, int out_size, void* d_ws, size_t ws_size,
                              hipStream_t stream)
{
    const float* x    = (const float*)d_in[0];
    const float* Wqkv = (const float*)d_in[1];
    const float* bqkv = (const float*)d_in[2];
    const float* Wo   = (const float*)d_in[3];
    const float* bo   = (const float*)d_in[4];
    const int*   pid  = (const int*)d_in[5];
    float* out = (float*)d_out;
    char* ws = (char*)d_ws;

    // workspace layout (byte offsets, peak 112 MB):
    //  [0,16M)   x2 ......... then Wo2t (after GEMM1)
    //  [16M,64M) Wq2t ....... then Q2 [16,32) K2 [32,48) Vt [48,56) A2 [56,72)
    //  [64M,112M) qkv fp32 .. dead after rope+tv (A2 tail overlaps it)
    const size_t MB = 1u << 20;
    unsigned short* x2   = (unsigned short*)(ws);
    unsigned short* Wq2t = (unsigned short*)(ws + 16 * MB);
    float*          qkv  = (float*)(ws + 64 * MB);
    unsigned short* Q2   = (unsigned short*)(ws + 16 * MB);
    unsigned short* K2   = (unsigned short*)(ws + 32 * MB);
    unsigned short* Vtb  = (unsigned short*)(ws + 48 * MB);
    unsigned short* Wo2t = (unsigned short*)(ws);
    unsigned short* A2   = (unsigned short*)(ws + 56 * MB);

    conv_x_kernel<<<4096, 256, 0, stream>>>(x, x2);
    tw_kernel<<<dim3(96, 32), 256, 0, stream>>>(Wqkv, Wq2t, 6144);
    gemm_split_kernel<<<768, 256, 0, stream>>>(x2, Wq2t, bqkv, qkv, 6144, 48, 768);
    rope_kernel<<<2048, 256, 0, stream>>>(qkv, pid, Q2, K2);
    tv_kernel<<<dim3(32, 32), 256, 0, stream>>>(qkv, Vtb);
    tw_kernel<<<dim3(32, 32), 256, 0, stream>>>(Wo, Wo2t, 2048);
    attn_kernel<<<512, 256, 0, stream>>>(Q2, K2, Vtb, A2);
    gemm_split_kernel<<<256, 256, 0, stream>>>(A2, Wo2t, bo, out, 2048, 16, 256);
}

// Round 4
// 498.751 us; speedup vs baseline: 3.4440x; 1.0322x over previous
//
#include <hip/hip_runtime.h>
#include <cmath>

typedef __attribute__((ext_vector_type(8))) short short8;
typedef __attribute__((ext_vector_type(4))) float f32x4;

#define S_LEN 2048
#define DM    2048

__device__ __forceinline__ unsigned short f2bf(float f) {
    unsigned u = __float_as_uint(f);
    u = (u + 0x7fffu + ((u >> 16) & 1u)) >> 16;
    return (unsigned short)u;
}
__device__ __forceinline__ float bf2f(unsigned short h) {
    return __uint_as_float(((unsigned)h) << 16);
}
__device__ __forceinline__ void gload16(const void* g, void* l) {
    __builtin_amdgcn_global_load_lds(
        (const __attribute__((address_space(1))) unsigned*)g,
        (__attribute__((address_space(3))) unsigned*)l, 16, 0, 0);
}

// ---------------------------------------------------------------------------
// x [2048][2048] fp32 -> x2 [2048][4096] bf16 ([hi(2048) | lo(2048)])
// ---------------------------------------------------------------------------
__global__ __launch_bounds__(256) void conv_x_kernel(
    const float* __restrict__ x, unsigned short* __restrict__ x2)
{
    const int idx = blockIdx.x * 256 + threadIdx.x;  // 4 floats each
    const int r = idx >> 9;
    const int c = (idx & 511) << 2;
    float4 v = *(const float4*)(x + (size_t)r * 2048 + c);
    unsigned short h0 = f2bf(v.x), h1 = f2bf(v.y), h2 = f2bf(v.z), h3 = f2bf(v.w);
    ushort4 hv = make_ushort4(h0, h1, h2, h3);
    ushort4 lv = make_ushort4(f2bf(v.x - bf2f(h0)), f2bf(v.y - bf2f(h1)),
                              f2bf(v.z - bf2f(h2)), f2bf(v.w - bf2f(h3)));
    *(ushort4*)(x2 + (size_t)r * 4096 + c) = hv;
    *(ushort4*)(x2 + (size_t)r * 4096 + 2048 + c) = lv;
}

// ---------------------------------------------------------------------------
// W fp32 [2048][N] -> Wt [N][4096] bf16, Wt[n][k]=hi(W[k][n]), [n][2048+k]=lo
// ---------------------------------------------------------------------------
__global__ __launch_bounds__(256) void tw_kernel(
    const float* __restrict__ W, unsigned short* __restrict__ Wt, int N)
{
    __shared__ float T[64][65];
    const int t = threadIdx.x;
    const int bx = blockIdx.x;   // n block
    const int by = blockIdx.y;   // k block (32)
    {
        const int c = (t & 15) * 4;
        const int r0 = t >> 4;
#pragma unroll
        for (int i = 0; i < 4; ++i) {
            const int r = r0 + i * 16;
            float4 v = *(const float4*)(W + (size_t)(by * 64 + r) * N + bx * 64 + c);
            T[r][c] = v.x; T[r][c + 1] = v.y; T[r][c + 2] = v.z; T[r][c + 3] = v.w;
        }
    }
    __syncthreads();
    const int n = t >> 2;
    const int kq = (t & 3) * 16;
    unsigned hp[8], lp[8];
#pragma unroll
    for (int j = 0; j < 16; j += 2) {
        float f0 = T[kq + j][n], f1 = T[kq + j + 1][n];
        unsigned short a0 = f2bf(f0), a1 = f2bf(f1);
        unsigned short b0 = f2bf(f0 - bf2f(a0)), b1 = f2bf(f1 - bf2f(a1));
        hp[j >> 1] = (unsigned)a0 | ((unsigned)a1 << 16);
        lp[j >> 1] = (unsigned)b0 | ((unsigned)b1 << 16);
    }
    unsigned short* dst = Wt + (size_t)(bx * 64 + n) * 4096 + by * 64 + kq;
    *(uint4*)(dst)            = make_uint4(hp[0], hp[1], hp[2], hp[3]);
    *(uint4*)(dst + 8)        = make_uint4(hp[4], hp[5], hp[6], hp[7]);
    *(uint4*)(dst + 2048)     = make_uint4(lp[0], lp[1], lp[2], lp[3]);
    *(uint4*)(dst + 2048 + 8) = make_uint4(lp[4], lp[5], lp[6], lp[7]);
}

// ---------------------------------------------------------------------------
// split-bf16 GEMM with per-block term count:
//   nt = (bx < nbx3) ? nt_lo : nt_hi; terms: 0=Ah*Bh, 1=Ah*Bl, 2=Al*Bh
// 128x128 tile, BK=64, 4 waves, global_load_lds w=16, XOR granule swizzle.
// ---------------------------------------------------------------------------
__global__ __launch_bounds__(256, 2) void gemm_split_kernel(
    const unsigned short* __restrict__ A2, const unsigned short* __restrict__ B2t,
    const float* __restrict__ bias, float* __restrict__ C, int N, int nbx, int nwg,
    int nbx3, int nt_lo, int nt_hi)
{
    __shared__ unsigned short As[128 * 64];
    __shared__ unsigned short Bs[128 * 64];
    const int wk = ((blockIdx.x & 7) * (nwg >> 3)) + (blockIdx.x >> 3);  // XCD swizzle
    const int bx = wk % nbx, by = wk / nbx;
    const int tid = threadIdx.x;
    const int lane = tid & 63, wv = tid >> 6;
    const int lr = lane & 15, hi8 = lane >> 4, kx = lane & 7;
    const int wm = wv >> 1, wn = wv & 1;
    const int nt = (bx < nbx3) ? nt_lo : nt_hi;

    f32x4 acc[4][4];
#pragma unroll
    for (int i = 0; i < 4; ++i)
#pragma unroll
        for (int j = 0; j < 4; ++j) acc[i][j] = f32x4{0.f, 0.f, 0.f, 0.f};

    int ldso[4]; size_t goff[4];
#pragma unroll
    for (int i = 0; i < 4; ++i) {
        const int gr = i * 256 + tid;        // 16B granule id (1024 per tile)
        const int rr = gr >> 3, ss = gr & 7;
        const int gg = ss ^ (rr & 7);        // inverse swizzle on source
        ldso[i] = gr * 8;
        goff[i] = (size_t)rr * 4096 + gg * 8;
    }

    const unsigned short* Abase = A2 + (size_t)by * 128 * 4096;
    const unsigned short* Bbase = B2t + (size_t)bx * 128 * 4096;

    for (int term = 0; term < nt; ++term) {
        const unsigned short* Ag = Abase + (term == 2 ? 2048 : 0);
        const unsigned short* Bg = Bbase + (term == 1 ? 2048 : 0);
        for (int s32 = 0; s32 < 32; ++s32) {
#pragma unroll
            for (int i = 0; i < 4; ++i) gload16(Ag + goff[i], &As[ldso[i]]);
#pragma unroll
            for (int i = 0; i < 4; ++i) gload16(Bg + goff[i], &Bs[ldso[i]]);
            __syncthreads();   // compiler drains vmcnt here -> tiles ready
#pragma unroll
            for (int kc = 0; kc < 2; ++kc) {
                const int slot8 = ((kc * 4 + hi8) ^ kx) * 8;
                short8 aF[4], bF[4];
#pragma unroll
                for (int mt = 0; mt < 4; ++mt)
                    aF[mt] = *(const short8*)&As[(wm * 64 + mt * 16 + lr) * 64 + slot8];
#pragma unroll
                for (int nt2 = 0; nt2 < 4; ++nt2)
                    bF[nt2] = *(const short8*)&Bs[(wn * 64 + nt2 * 16 + lr) * 64 + slot8];
#pragma unroll
                for (int mt = 0; mt < 4; ++mt)
#pragma unroll
                    for (int nt2 = 0; nt2 < 4; ++nt2)
                        acc[mt][nt2] = __builtin_amdgcn_mfma_f32_16x16x32_bf16(
                            aF[mt], bF[nt2], acc[mt][nt2], 0, 0, 0);
            }
            __syncthreads();   // all reads done before next overwrite
            Ag += 64; Bg += 64;
        }
    }

#pragma unroll
    for (int nt2 = 0; nt2 < 4; ++nt2) {
        const int col = bx * 128 + wn * 64 + nt2 * 16 + lr;
        const float bv = bias[col];
#pragma unroll
        for (int mt = 0; mt < 4; ++mt)
#pragma unroll
            for (int r = 0; r < 4; ++r) {
                const int row = by * 128 + wm * 64 + mt * 16 + hi8 * 4 + r;
                C[(size_t)row * N + col] = acc[mt][nt2][r] + bv;
            }
    }
}

// ---------------------------------------------------------------------------
// Dual RoPE: qkv fp32 [S][6144] -> Q2/K2 [H][S][256] bf16 ([hi(128)|lo(128)])
// ---------------------------------------------------------------------------
__global__ __launch_bounds__(256) void rope_kernel(
    const float* __restrict__ qkv, const int* __restrict__ pid,
    unsigned short* __restrict__ Q2, unsigned short* __restrict__ K2)
{
    const int s = blockIdx.x, t = threadIdx.x;
    const int h = t >> 4, rem = t & 15, b = rem >> 3, e4 = (rem & 7) * 4;
    const size_t rb = (size_t)s * 6144;
    const int cq = h * 128 + b * 64 + e4;

    float4 q1 = *(const float4*)(qkv + rb + cq);
    float4 q2v = *(const float4*)(qkv + rb + cq + 32);
    float4 k1 = *(const float4*)(qkv + rb + 2048 + cq);
    float4 k2v = *(const float4*)(qkv + rb + 2048 + cq + 32);
    const float pos = (float)((b == 0) ? pid[s] : pid[2048 + s]);

    float qa[4] = {q1.x, q1.y, q1.z, q1.w};
    float qb[4] = {q2v.x, q2v.y, q2v.z, q2v.w};
    float ka[4] = {k1.x, k1.y, k1.z, k1.w};
    float kb[4] = {k2v.x, k2v.y, k2v.z, k2v.w};
    float qo1[4], qo2[4], ko1[4], ko2[4];
#pragma unroll
    for (int u = 0; u < 4; ++u) {
        const float j = (float)(e4 + u);
        const float invf = powf(10000.f, -j * (1.f / 32.f));
        const float ang = pos * invf;
        float sn, cs;
        sincosf(ang, &sn, &cs);
        qo1[u] = qa[u] * cs - qb[u] * sn;
        qo2[u] = qb[u] * cs + qa[u] * sn;
        ko1[u] = ka[u] * cs - kb[u] * sn;
        ko2[u] = kb[u] * cs + ka[u] * sn;
    }

    unsigned short* qd = Q2 + ((size_t)h * 2048 + s) * 256 + b * 64 + e4;
    unsigned short* kd = K2 + ((size_t)h * 2048 + s) * 256 + b * 64 + e4;
    ushort4 t4;
#pragma unroll
    for (int pass = 0; pass < 2; ++pass) {
        float* v1 = pass ? ko1 : qo1;
        float* v2 = pass ? ko2 : qo2;
        unsigned short* d = pass ? kd : qd;
        unsigned short hh[8], ll[8];
#pragma unroll
        for (int u = 0; u < 4; ++u) {
            hh[u] = f2bf(v1[u]);     ll[u] = f2bf(v1[u] - bf2f(hh[u]));
            hh[4 + u] = f2bf(v2[u]); ll[4 + u] = f2bf(v2[u] - bf2f(hh[4 + u]));
        }
        t4 = make_ushort4(hh[0], hh[1], hh[2], hh[3]); *(ushort4*)(d) = t4;
        t4 = make_ushort4(hh[4], hh[5], hh[6], hh[7]); *(ushort4*)(d + 32) = t4;
        t4 = make_ushort4(ll[0], ll[1], ll[2], ll[3]); *(ushort4*)(d + 128) = t4;
        t4 = make_ushort4(ll[4], ll[5], ll[6], ll[7]); *(ushort4*)(d + 160) = t4;
    }
}

// ---------------------------------------------------------------------------
// V transpose: qkv cols [4096,6144) fp32 -> Vt [H][128][S] bf16
// ---------------------------------------------------------------------------
__global__ __launch_bounds__(256) void tv_kernel(
    const float* __restrict__ qkv, unsigned short* __restrict__ Vt)
{
    __shared__ float T[64][65];
    const int t = threadIdx.x;
    const int bs = blockIdx.x;   // s block (32)
    const int bc = blockIdx.y;   // v-col block (32)
    {
        const int c = (t & 15) * 4;
        const int r0 = t >> 4;
#pragma unroll
        for (int i = 0; i < 4; ++i) {
            const int r = r0 + i * 16;
            float4 v = *(const float4*)(qkv + (size_t)(bs * 64 + r) * 6144 + 4096 + bc * 64 + c);
            T[r][c] = v.x; T[r][c + 1] = v.y; T[r][c + 2] = v.z; T[r][c + 3] = v.w;
        }
    }
    __syncthreads();
    const int d = t >> 2;
    const int sq = (t & 3) * 16;
    const int gcol = bc * 64 + d;
    const int h = gcol >> 7, dd = gcol & 127;
    unsigned hp[8];
#pragma unroll
    for (int j = 0; j < 16; j += 2) {
        hp[j >> 1] = (unsigned)f2bf(T[sq + j][d]) | ((unsigned)f2bf(T[sq + j + 1][d]) << 16);
    }
    unsigned short* dst = Vt + ((size_t)h * 128 + dd) * 2048 + bs * 64 + sq;
    *(uint4*)(dst)     = make_uint4(hp[0], hp[1], hp[2], hp[3]);
    *(uint4*)(dst + 8) = make_uint4(hp[4], hp[5], hp[6], hp[7]);
}

// ---------------------------------------------------------------------------
// MFMA flash attention v2. Block = (head, 128-q-tile), 4 waves x 32 q rows
// (2 row-groups of 16). QK^T split-bf16 with Khi fragment reuse (each Khi
// read feeds 4 MFMAs); PV plain bf16, V frags shared across row-groups.
// K/V double-buffered in LDS (1 barrier per kt); Q hoisted in registers.
// Writes only the hi part of the output (GEMM2 runs 2-term on B-side).
// ---------------------------------------------------------------------------
#define K_ELEMS 16384
#define V_ELEMS 8192
#define P_ELEMS 2304   // 32 rows * 72
#define ATTN_LDS_BYTES ((2 * K_ELEMS + 2 * V_ELEMS + 4 * P_ELEMS) * 2)

__global__ __launch_bounds__(256, 1) void attn_kernel(
    const unsigned short* __restrict__ Q2, const unsigned short* __restrict__ K2,
    const unsigned short* __restrict__ Vt, unsigned short* __restrict__ A2)
{
    extern __shared__ unsigned short sm[];
    unsigned short* KsB = sm;                          // 2 x 16384
    unsigned short* VsB = sm + 2 * K_ELEMS;            // 2 x 8192
    unsigned short* Ps  = sm + 2 * K_ELEMS + 2 * V_ELEMS;

    const int bid = blockIdx.x;
    const int idx = bid >> 3;
    const int h = ((bid & 7) << 1) | (idx >> 4);   // 2 heads per XCD
    const int qt = idx & 15;
    const int tid = threadIdx.x;
    const int w = tid >> 6, lane = tid & 63;
    const int lr = lane & 15, hi8 = lane >> 4, kx = lane & 7;

    // Q fragments for 2 row-groups: rows qt*128 + w*32 + rg*16 + lr
    short8 qf[2][8];
#pragma unroll
    for (int rg = 0; rg < 2; ++rg) {
        const unsigned short* Qr =
            Q2 + ((size_t)h * 2048 + qt * 128 + w * 32 + rg * 16 + lr) * 256;
#pragma unroll
        for (int c = 0; c < 4; ++c) {
            qf[rg][c]     = *(const short8*)(Qr + c * 32 + hi8 * 8);        // hi
            qf[rg][4 + c] = *(const short8*)(Qr + 128 + c * 32 + hi8 * 8);  // lo
        }
    }

    f32x4 acco[2][8];
    float mrun[2][4], lrun[2][4];
#pragma unroll
    for (int rg = 0; rg < 2; ++rg) {
#pragma unroll
        for (int i = 0; i < 8; ++i) acco[rg][i] = f32x4{0.f, 0.f, 0.f, 0.f};
#pragma unroll
        for (int r = 0; r < 4; ++r) { mrun[rg][r] = -INFINITY; lrun[rg][r] = 0.f; }
    }

    // staging offset tables (pre-swizzled global source, linear LDS dest)
    int kl[8], kg[8];
#pragma unroll
    for (int i = 0; i < 8; ++i) {
        const int gr = i * 256 + tid;
        const int rr = gr >> 5, ss = gr & 31;
        const int gg = (ss & 24) | ((ss & 7) ^ (rr & 7));
        kl[i] = gr * 8;
        kg[i] = rr * 256 + gg * 8;
    }
    int vl[4], vg[4];
#pragma unroll
    for (int i = 0; i < 4; ++i) {
        const int gr = i * 256 + tid;
        const int rr = gr >> 3, ss = gr & 7;
        const int gg = ss ^ (rr & 7);
        vl[i] = gr * 8;
        vg[i] = rr * 2048 + gg * 8;
    }

    const unsigned short* Kh = K2 + (size_t)h * 2048 * 256;
    const unsigned short* Vh = Vt + (size_t)h * 128 * 2048;
    unsigned short* Pw = Ps + w * P_ELEMS;

    // prologue: stage tile 0 into buffer 0
    {
        const unsigned short* Kg = Kh;
        const unsigned short* Vg = Vh;
#pragma unroll
        for (int i = 0; i < 8; ++i) gload16(Kg + kg[i], &KsB[kl[i]]);
#pragma unroll
        for (int i = 0; i < 4; ++i) gload16(Vg + vg[i], &VsB[vl[i]]);
    }
    __syncthreads();

    for (int kt = 0; kt < 32; ++kt) {
        const int cur = kt & 1;
        // issue next tile's async loads into the other buffer
        if (kt + 1 < 32) {
            const unsigned short* Kg = Kh + (size_t)(kt + 1) * K_ELEMS;
            const unsigned short* Vg = Vh + (kt + 1) * 64;
            unsigned short* Kd = KsB + (cur ^ 1) * K_ELEMS;
            unsigned short* Vd = VsB + (cur ^ 1) * V_ELEMS;
#pragma unroll
            for (int i = 0; i < 8; ++i) gload16(Kg + kg[i], &Kd[kl[i]]);
#pragma unroll
            for (int i = 0; i < 4; ++i) gload16(Vg + vg[i], &Vd[vl[i]]);
        }
        const unsigned short* Kc = KsB + cur * K_ELEMS;
        const unsigned short* Vc = VsB + cur * V_ELEMS;

        // ---- QK^T: split-bf16 with Khi reuse (Khi frag -> 4 MFMAs) ----
        f32x4 sacc[2][4];
#pragma unroll
        for (int rg = 0; rg < 2; ++rg)
#pragma unroll
            for (int ct = 0; ct < 4; ++ct) sacc[rg][ct] = f32x4{0.f, 0.f, 0.f, 0.f};

#pragma unroll
        for (int ct = 0; ct < 4; ++ct) {
            const int rowb = (ct * 16 + lr) * 256;
#pragma unroll
            for (int c = 0; c < 4; ++c) {       // Khi slices
                const int g = c * 4 + hi8;
                const int slot = (g & 8) | ((g & 7) ^ kx);
                short8 kf = *(const short8*)&Kc[rowb + slot * 8];
                sacc[0][ct] = __builtin_amdgcn_mfma_f32_16x16x32_bf16(qf[0][c], kf, sacc[0][ct], 0, 0, 0);
                sacc[1][ct] = __builtin_amdgcn_mfma_f32_16x16x32_bf16(qf[1][c], kf, sacc[1][ct], 0, 0, 0);
                sacc[0][ct] = __builtin_amdgcn_mfma_f32_16x16x32_bf16(qf[0][4 + c], kf, sacc[0][ct], 0, 0, 0);
                sacc[1][ct] = __builtin_amdgcn_mfma_f32_16x16x32_bf16(qf[1][4 + c], kf, sacc[1][ct], 0, 0, 0);
            }
#pragma unroll
            for (int c = 0; c < 4; ++c) {       // Klo slices (x Qhi)
                const int g = c * 4 + hi8;
                const int slot = 16 | (g & 8) | ((g & 7) ^ kx);
                short8 kf = *(const short8*)&Kc[rowb + slot * 8];
                sacc[0][ct] = __builtin_amdgcn_mfma_f32_16x16x32_bf16(qf[0][c], kf, sacc[0][ct], 0, 0, 0);
                sacc[1][ct] = __builtin_amdgcn_mfma_f32_16x16x32_bf16(qf[1][c], kf, sacc[1][ct], 0, 0, 0);
            }
        }

        // ---- online softmax (rows hi8*4+r per row-group) ----
        float scl[2][4];
#pragma unroll
        for (int rg = 0; rg < 2; ++rg) {
#pragma unroll
            for (int r = 0; r < 4; ++r) {
                float tm = fmaxf(fmaxf(sacc[rg][0][r], sacc[rg][1][r]),
                                 fmaxf(sacc[rg][2][r], sacc[rg][3][r]));
                tm = fmaxf(tm, __shfl_xor(tm, 1));
                tm = fmaxf(tm, __shfl_xor(tm, 2));
                tm = fmaxf(tm, __shfl_xor(tm, 4));
                tm = fmaxf(tm, __shfl_xor(tm, 8));
                const float mnew = fmaxf(mrun[rg][r], tm);
                const float sc = __expf(mrun[rg][r] - mnew);
                float pv[4], ps = 0.f;
#pragma unroll
                for (int ct = 0; ct < 4; ++ct) {
                    pv[ct] = __expf(sacc[rg][ct][r] - mnew);
                    ps += pv[ct];
                }
                ps += __shfl_xor(ps, 1); ps += __shfl_xor(ps, 2);
                ps += __shfl_xor(ps, 4); ps += __shfl_xor(ps, 8);
                lrun[rg][r] = lrun[rg][r] * sc + ps;
                mrun[rg][r] = mnew;
                scl[rg][r] = sc;
#pragma unroll
                for (int ct = 0; ct < 4; ++ct)
                    Pw[(rg * 16 + hi8 * 4 + r) * 72 + ct * 16 + lr] = f2bf(pv[ct]);
            }
#pragma unroll
            for (int dt = 0; dt < 8; ++dt)
#pragma unroll
                for (int r = 0; r < 4; ++r) acco[rg][dt][r] *= scl[rg][r];
        }

        // ---- PV (plain bf16); V frags shared across row-groups ----
        short8 pf0[2], pf1[2];
#pragma unroll
        for (int rg = 0; rg < 2; ++rg) {
            pf0[rg] = *(const short8*)&Pw[(rg * 16 + lr) * 72 + hi8 * 8];
            pf1[rg] = *(const short8*)&Pw[(rg * 16 + lr) * 72 + 32 + hi8 * 8];
        }
#pragma unroll
        for (int dt = 0; dt < 8; ++dt) {
            const int rowb = (dt * 16 + lr) * 64;
            short8 vf0 = *(const short8*)&Vc[rowb + ((0 + hi8) ^ kx) * 8];
            short8 vf1 = *(const short8*)&Vc[rowb + ((4 + hi8) ^ kx) * 8];
#pragma unroll
            for (int rg = 0; rg < 2; ++rg) {
                acco[rg][dt] = __builtin_amdgcn_mfma_f32_16x16x32_bf16(pf0[rg], vf0, acco[rg][dt], 0, 0, 0);
                acco[rg][dt] = __builtin_amdgcn_mfma_f32_16x16x32_bf16(pf1[rg], vf1, acco[rg][dt], 0, 0, 0);
            }
        }
        __syncthreads();   // drains prefetch loads + guards buffer overwrite
    }

    // epilogue: normalize, write hi-only output row
#pragma unroll
    for (int rg = 0; rg < 2; ++rg)
#pragma unroll
        for (int dt = 0; dt < 8; ++dt) {
            const int n = h * 128 + dt * 16 + lr;
#pragma unroll
            for (int r = 0; r < 4; ++r) {
                const int srow = qt * 128 + w * 32 + rg * 16 + hi8 * 4 + r;
                A2[(size_t)srow * 4096 + n] = f2bf(acco[rg][dt][r] / lrun[rg][r]);
            }
        }
}

// ---------------------------------------------------------------------------
// launch
// ---------------------------------------------------------------------------
extern "C" void kernel_launch(void* const* d_in, const int* in_sizes, int n_in,
                              void* d_out, int out_size, void* d_ws, size_t ws_size,
                              hipStream_t stream)
{
    const float* x    = (const float*)d_in[0];
    const float* Wqkv = (const float*)d_in[1];
    const float* bqkv = (const float*)d_in[2];
    const float* Wo   = (const float*)d_in[3];
    const float* bo   = (const float*)d_in[4];
    const int*   pid  = (const int*)d_in[5];
    float* out = (float*)d_out;
    char* ws = (char*)d_ws;

    // workspace layout (byte offsets, peak 112 MB):
    //  [0,16M)   x2 ......... then Wo2t (after GEMM1)
    //  [16M,64M) Wq2t ....... then Q2 [16,32) K2 [32,48) Vt [48,56) A2 [56,72)
    //  [64M,112M) qkv fp32 .. dead after rope+tv (A2 tail overlaps it)
    const size_t MB = 1u << 20;
    unsigned short* x2   = (unsigned short*)(ws);
    unsigned short* Wq2t = (unsigned short*)(ws + 16 * MB);
    float*          qkv  = (float*)(ws + 64 * MB);
    unsigned short* Q2   = (unsigned short*)(ws + 16 * MB);
    unsigned short* K2   = (unsigned short*)(ws + 32 * MB);
    unsigned short* Vtb  = (unsigned short*)(ws + 48 * MB);
    unsigned short* Wo2t = (unsigned short*)(ws);
    unsigned short* A2   = (unsigned short*)(ws + 56 * MB);

    conv_x_kernel<<<4096, 256, 0, stream>>>(x, x2);
    tw_kernel<<<dim3(96, 32), 256, 0, stream>>>(Wqkv, Wq2t, 6144);
    // QKV projection: 3-term for Q/K columns (bx<32), 1-term (plain bf16) for V
    gemm_split_kernel<<<768, 256, 0, stream>>>(x2, Wq2t, bqkv, qkv, 6144, 48, 768, 32, 3, 1);
    rope_kernel<<<2048, 256, 0, stream>>>(qkv, pid, Q2, K2);
    tv_kernel<<<dim3(32, 32), 256, 0, stream>>>(qkv, Vtb);
    tw_kernel<<<dim3(32, 32), 256, 0, stream>>>(Wo, Wo2t, 2048);

    hipFuncSetAttribute(reinterpret_cast<const void*>(attn_kernel),
                        hipFuncAttributeMaxDynamicSharedMemorySize, ATTN_LDS_BYTES);
    attn_kernel<<<256, 256, ATTN_LDS_BYTES, stream>>>(Q2, K2, Vtb, A2);

    // output projection: 2-term (Ah*Bh + Ah*Bl); A-lo never read
    gemm_split_kernel<<<256, 256, 0, stream>>>(A2, Wo2t, bo, out, 2048, 16, 256, 16, 2, 2);
}

// Round 6
// 482.199 us; speedup vs baseline: 3.5622x; 1.0343x over previous
//
#include <hip/hip_runtime.h>
#include <cmath>

typedef __attribute__((ext_vector_type(8))) short short8;
typedef __attribute__((ext_vector_type(4))) float f32x4;

#define S_LEN 2048
#define DM    2048

__device__ __forceinline__ unsigned short f2bf(float f) {
    unsigned u = __float_as_uint(f);
    u = (u + 0x7fffu + ((u >> 16) & 1u)) >> 16;
    return (unsigned short)u;
}
__device__ __forceinline__ float bf2f(unsigned short h) {
    return __uint_as_float(((unsigned)h) << 16);
}
__device__ __forceinline__ void gload16(const void* g, void* l) {
    __builtin_amdgcn_global_load_lds(
        (const __attribute__((address_space(1))) unsigned*)g,
        (__attribute__((address_space(3))) unsigned*)l, 16, 0, 0);
}

// ---------------------------------------------------------------------------
// x [2048][2048] fp32 -> x2 [2048][4096] bf16 ([hi(2048) | lo(2048)])
// ---------------------------------------------------------------------------
__global__ __launch_bounds__(256) void conv_x_kernel(
    const float* __restrict__ x, unsigned short* __restrict__ x2)
{
    const int idx = blockIdx.x * 256 + threadIdx.x;  // 4 floats each
    const int r = idx >> 9;
    const int c = (idx & 511) << 2;
    float4 v = *(const float4*)(x + (size_t)r * 2048 + c);
    unsigned short h0 = f2bf(v.x), h1 = f2bf(v.y), h2 = f2bf(v.z), h3 = f2bf(v.w);
    ushort4 hv = make_ushort4(h0, h1, h2, h3);
    ushort4 lv = make_ushort4(f2bf(v.x - bf2f(h0)), f2bf(v.y - bf2f(h1)),
                              f2bf(v.z - bf2f(h2)), f2bf(v.w - bf2f(h3)));
    *(ushort4*)(x2 + (size_t)r * 4096 + c) = hv;
    *(ushort4*)(x2 + (size_t)r * 4096 + 2048 + c) = lv;
}

// ---------------------------------------------------------------------------
// W fp32 [2048][N] -> Wt [N][4096] bf16, Wt[n][k]=hi(W[k][n]), [n][2048+k]=lo
// ---------------------------------------------------------------------------
__global__ __launch_bounds__(256) void tw_kernel(
    const float* __restrict__ W, unsigned short* __restrict__ Wt, int N)
{
    __shared__ float T[64][65];
    const int t = threadIdx.x;
    const int bx = blockIdx.x;   // n block
    const int by = blockIdx.y;   // k block (32)
    {
        const int c = (t & 15) * 4;
        const int r0 = t >> 4;
#pragma unroll
        for (int i = 0; i < 4; ++i) {
            const int r = r0 + i * 16;
            float4 v = *(const float4*)(W + (size_t)(by * 64 + r) * N + bx * 64 + c);
            T[r][c] = v.x; T[r][c + 1] = v.y; T[r][c + 2] = v.z; T[r][c + 3] = v.w;
        }
    }
    __syncthreads();
    const int n = t >> 2;
    const int kq = (t & 3) * 16;
    unsigned hp[8], lp[8];
#pragma unroll
    for (int j = 0; j < 16; j += 2) {
        float f0 = T[kq + j][n], f1 = T[kq + j + 1][n];
        unsigned short a0 = f2bf(f0), a1 = f2bf(f1);
        unsigned short b0 = f2bf(f0 - bf2f(a0)), b1 = f2bf(f1 - bf2f(a1));
        hp[j >> 1] = (unsigned)a0 | ((unsigned)a1 << 16);
        lp[j >> 1] = (unsigned)b0 | ((unsigned)b1 << 16);
    }
    unsigned short* dst = Wt + (size_t)(bx * 64 + n) * 4096 + by * 64 + kq;
    *(uint4*)(dst)            = make_uint4(hp[0], hp[1], hp[2], hp[3]);
    *(uint4*)(dst + 8)        = make_uint4(hp[4], hp[5], hp[6], hp[7]);
    *(uint4*)(dst + 2048)     = make_uint4(lp[0], lp[1], lp[2], lp[3]);
    *(uint4*)(dst + 2048 + 8) = make_uint4(lp[4], lp[5], lp[6], lp[7]);
}

// ---------------------------------------------------------------------------
// split-bf16 GEMM with per-block term count:
//   nt = (bx < nbx3) ? nt_lo : nt_hi; terms: 0=Ah*Bh, 1=Ah*Bl, 2=Al*Bh
// 128x128 tile, BK=64, 4 waves, global_load_lds w=16, XOR granule swizzle.
// ---------------------------------------------------------------------------
__global__ __launch_bounds__(256, 2) void gemm_split_kernel(
    const unsigned short* __restrict__ A2, const unsigned short* __restrict__ B2t,
    const float* __restrict__ bias, float* __restrict__ C, int N, int nbx, int nwg,
    int nbx3, int nt_lo, int nt_hi)
{
    __shared__ unsigned short As[128 * 64];
    __shared__ unsigned short Bs[128 * 64];
    const int wk = ((blockIdx.x & 7) * (nwg >> 3)) + (blockIdx.x >> 3);  // XCD swizzle
    const int bx = wk % nbx, by = wk / nbx;
    const int tid = threadIdx.x;
    const int lane = tid & 63, wv = tid >> 6;
    const int lr = lane & 15, hi8 = lane >> 4, kx = lane & 7;
    const int wm = wv >> 1, wn = wv & 1;
    const int nt = (bx < nbx3) ? nt_lo : nt_hi;

    f32x4 acc[4][4];
#pragma unroll
    for (int i = 0; i < 4; ++i)
#pragma unroll
        for (int j = 0; j < 4; ++j) acc[i][j] = f32x4{0.f, 0.f, 0.f, 0.f};

    int ldso[4]; size_t goff[4];
#pragma unroll
    for (int i = 0; i < 4; ++i) {
        const int gr = i * 256 + tid;        // 16B granule id (1024 per tile)
        const int rr = gr >> 3, ss = gr & 7;
        const int gg = ss ^ (rr & 7);        // inverse swizzle on source
        ldso[i] = gr * 8;
        goff[i] = (size_t)rr * 4096 + gg * 8;
    }

    const unsigned short* Abase = A2 + (size_t)by * 128 * 4096;
    const unsigned short* Bbase = B2t + (size_t)bx * 128 * 4096;

    for (int term = 0; term < nt; ++term) {
        const unsigned short* Ag = Abase + (term == 2 ? 2048 : 0);
        const unsigned short* Bg = Bbase + (term == 1 ? 2048 : 0);
        for (int s32 = 0; s32 < 32; ++s32) {
#pragma unroll
            for (int i = 0; i < 4; ++i) gload16(Ag + goff[i], &As[ldso[i]]);
#pragma unroll
            for (int i = 0; i < 4; ++i) gload16(Bg + goff[i], &Bs[ldso[i]]);
            __syncthreads();   // compiler drains vmcnt here -> tiles ready
#pragma unroll
            for (int kc = 0; kc < 2; ++kc) {
                const int slot8 = ((kc * 4 + hi8) ^ kx) * 8;
                short8 aF[4], bF[4];
#pragma unroll
                for (int mt = 0; mt < 4; ++mt)
                    aF[mt] = *(const short8*)&As[(wm * 64 + mt * 16 + lr) * 64 + slot8];
#pragma unroll
                for (int nt2 = 0; nt2 < 4; ++nt2)
                    bF[nt2] = *(const short8*)&Bs[(wn * 64 + nt2 * 16 + lr) * 64 + slot8];
#pragma unroll
                for (int mt = 0; mt < 4; ++mt)
#pragma unroll
                    for (int nt2 = 0; nt2 < 4; ++nt2)
                        acc[mt][nt2] = __builtin_amdgcn_mfma_f32_16x16x32_bf16(
                            aF[mt], bF[nt2], acc[mt][nt2], 0, 0, 0);
            }
            __syncthreads();   // all reads done before next overwrite
            Ag += 64; Bg += 64;
        }
    }

#pragma unroll
    for (int nt2 = 0; nt2 < 4; ++nt2) {
        const int col = bx * 128 + wn * 64 + nt2 * 16 + lr;
        const float bv = bias[col];
#pragma unroll
        for (int mt = 0; mt < 4; ++mt)
#pragma unroll
            for (int r = 0; r < 4; ++r) {
                const int row = by * 128 + wm * 64 + mt * 16 + hi8 * 4 + r;
                C[(size_t)row * N + col] = acc[mt][nt2][r] + bv;
            }
    }
}

// ---------------------------------------------------------------------------
// Dual RoPE: qkv fp32 [S][6144] -> Q2/K2 [H][S][256] bf16 ([hi(128)|lo(128)])
// ---------------------------------------------------------------------------
__global__ __launch_bounds__(256) void rope_kernel(
    const float* __restrict__ qkv, const int* __restrict__ pid,
    unsigned short* __restrict__ Q2, unsigned short* __restrict__ K2)
{
    const int s = blockIdx.x, t = threadIdx.x;
    const int h = t >> 4, rem = t & 15, b = rem >> 3, e4 = (rem & 7) * 4;
    const size_t rb = (size_t)s * 6144;
    const int cq = h * 128 + b * 64 + e4;

    float4 q1 = *(const float4*)(qkv + rb + cq);
    float4 q2v = *(const float4*)(qkv + rb + cq + 32);
    float4 k1 = *(const float4*)(qkv + rb + 2048 + cq);
    float4 k2v = *(const float4*)(qkv + rb + 2048 + cq + 32);
    const float pos = (float)((b == 0) ? pid[s] : pid[2048 + s]);

    float qa[4] = {q1.x, q1.y, q1.z, q1.w};
    float qb[4] = {q2v.x, q2v.y, q2v.z, q2v.w};
    float ka[4] = {k1.x, k1.y, k1.z, k1.w};
    float kb[4] = {k2v.x, k2v.y, k2v.z, k2v.w};
    float qo1[4], qo2[4], ko1[4], ko2[4];
#pragma unroll
    for (int u = 0; u < 4; ++u) {
        const float j = (float)(e4 + u);
        const float invf = powf(10000.f, -j * (1.f / 32.f));
        const float ang = pos * invf;
        float sn, cs;
        sincosf(ang, &sn, &cs);
        qo1[u] = qa[u] * cs - qb[u] * sn;
        qo2[u] = qb[u] * cs + qa[u] * sn;
        ko1[u] = ka[u] * cs - kb[u] * sn;
        ko2[u] = kb[u] * cs + ka[u] * sn;
    }

    unsigned short* qd = Q2 + ((size_t)h * 2048 + s) * 256 + b * 64 + e4;
    unsigned short* kd = K2 + ((size_t)h * 2048 + s) * 256 + b * 64 + e4;
    ushort4 t4;
#pragma unroll
    for (int pass = 0; pass < 2; ++pass) {
        float* v1 = pass ? ko1 : qo1;
        float* v2 = pass ? ko2 : qo2;
        unsigned short* d = pass ? kd : qd;
        unsigned short hh[8], ll[8];
#pragma unroll
        for (int u = 0; u < 4; ++u) {
            hh[u] = f2bf(v1[u]);     ll[u] = f2bf(v1[u] - bf2f(hh[u]));
            hh[4 + u] = f2bf(v2[u]); ll[4 + u] = f2bf(v2[u] - bf2f(hh[4 + u]));
        }
        t4 = make_ushort4(hh[0], hh[1], hh[2], hh[3]); *(ushort4*)(d) = t4;
        t4 = make_ushort4(hh[4], hh[5], hh[6], hh[7]); *(ushort4*)(d + 32) = t4;
        t4 = make_ushort4(ll[0], ll[1], ll[2], ll[3]); *(ushort4*)(d + 128) = t4;
        t4 = make_ushort4(ll[4], ll[5], ll[6], ll[7]); *(ushort4*)(d + 160) = t4;
    }
}

// ---------------------------------------------------------------------------
// V transpose: qkv cols [4096,6144) fp32 -> Vt [H][128][S] bf16
// ---------------------------------------------------------------------------
__global__ __launch_bounds__(256) void tv_kernel(
    const float* __restrict__ qkv, unsigned short* __restrict__ Vt)
{
    __shared__ float T[64][65];
    const int t = threadIdx.x;
    const int bs = blockIdx.x;   // s block (32)
    const int bc = blockIdx.y;   // v-col block (32)
    {
        const int c = (t & 15) * 4;
        const int r0 = t >> 4;
#pragma unroll
        for (int i = 0; i < 4; ++i) {
            const int r = r0 + i * 16;
            float4 v = *(const float4*)(qkv + (size_t)(bs * 64 + r) * 6144 + 4096 + bc * 64 + c);
            T[r][c] = v.x; T[r][c + 1] = v.y; T[r][c + 2] = v.z; T[r][c + 3] = v.w;
        }
    }
    __syncthreads();
    const int d = t >> 2;
    const int sq = (t & 3) * 16;
    const int gcol = bc * 64 + d;
    const int h = gcol >> 7, dd = gcol & 127;
    unsigned hp[8];
#pragma unroll
    for (int j = 0; j < 16; j += 2) {
        hp[j >> 1] = (unsigned)f2bf(T[sq + j][d]) | ((unsigned)f2bf(T[sq + j + 1][d]) << 16);
    }
    unsigned short* dst = Vt + ((size_t)h * 128 + dd) * 2048 + bs * 64 + sq;
    *(uint4*)(dst)     = make_uint4(hp[0], hp[1], hp[2], hp[3]);
    *(uint4*)(dst + 8) = make_uint4(hp[4], hp[5], hp[6], hp[7]);
}

// ---------------------------------------------------------------------------
// MFMA flash attention v3. 512 blocks = 16 heads x 32 q-tiles(64 rows) -->
// 2 blocks/CU (static 58 KB LDS), 8 waves/CU, cross-block pipe overlap.
// 4 waves x 16 q-rows; QK^T split-bf16 (Khi read shared by Qhi+Qlo MFMA);
// softmax fp32; PV plain bf16. Single-buffered K/V, 2 barriers per kt.
// Same per-row math order as v2 -> bit-identical output.
// ---------------------------------------------------------------------------
__global__ __launch_bounds__(256, 2) void attn_kernel(
    const unsigned short* __restrict__ Q2, const unsigned short* __restrict__ K2,
    const unsigned short* __restrict__ Vt, unsigned short* __restrict__ A2)
{
    __shared__ unsigned short Ks[64 * 256];    // 32 KB
    __shared__ unsigned short Vs[128 * 64];    // 16 KB
    __shared__ unsigned short Ps[4 * 16 * 72]; //  9 KB

    const int bid = blockIdx.x;
    const int idx = bid >> 3;
    const int h = ((bid & 7) << 1) | (idx >> 5);   // 2 heads per XCD -> L2-resident K/V
    const int qt = idx & 31;                       // 64-row q tile
    const int tid = threadIdx.x;
    const int w = tid >> 6, lane = tid & 63;
    const int lr = lane & 15, hi8 = lane >> 4, kx = lane & 7;

    // Q fragments (hi+lo) for this wave's 16 rows
    short8 qf[8];
    {
        const unsigned short* Qr =
            Q2 + ((size_t)h * 2048 + qt * 64 + w * 16 + lr) * 256;
#pragma unroll
        for (int c = 0; c < 4; ++c) {
            qf[c]     = *(const short8*)(Qr + c * 32 + hi8 * 8);        // hi
            qf[4 + c] = *(const short8*)(Qr + 128 + c * 32 + hi8 * 8);  // lo
        }
    }

    f32x4 acco[8];
    float mrun[4], lrun[4];
#pragma unroll
    for (int i = 0; i < 8; ++i) acco[i] = f32x4{0.f, 0.f, 0.f, 0.f};
#pragma unroll
    for (int r = 0; r < 4; ++r) { mrun[r] = -INFINITY; lrun[r] = 0.f; }

    // staging offset tables (pre-swizzled global source, linear LDS dest)
    int kl[8], kg[8];
#pragma unroll
    for (int i = 0; i < 8; ++i) {
        const int gr = i * 256 + tid;
        const int rr = gr >> 5, ss = gr & 31;
        const int gg = (ss & 24) | ((ss & 7) ^ (rr & 7));
        kl[i] = gr * 8;
        kg[i] = rr * 256 + gg * 8;
    }
    int vl[4], vg[4];
#pragma unroll
    for (int i = 0; i < 4; ++i) {
        const int gr = i * 256 + tid;
        const int rr = gr >> 3, ss = gr & 7;
        const int gg = ss ^ (rr & 7);
        vl[i] = gr * 8;
        vg[i] = rr * 2048 + gg * 8;
    }

    const unsigned short* Kh = K2 + (size_t)h * 2048 * 256;
    const unsigned short* Vh = Vt + (size_t)h * 128 * 2048;
    unsigned short* Pw = Ps + w * 16 * 72;

    for (int kt = 0; kt < 32; ++kt) {
        // stage K,V tile (async); barrier drains vmcnt -> data ready
        {
            const unsigned short* Kg = Kh + (size_t)kt * 16384;
            const unsigned short* Vg = Vh + kt * 64;
#pragma unroll
            for (int i = 0; i < 8; ++i) gload16(Kg + kg[i], &Ks[kl[i]]);
#pragma unroll
            for (int i = 0; i < 4; ++i) gload16(Vg + vg[i], &Vs[vl[i]]);
        }
        __syncthreads();

        // ---- QK^T: split-bf16 (Khi read feeds Qhi and Qlo MFMAs) ----
        f32x4 sacc[4];
#pragma unroll
        for (int ct = 0; ct < 4; ++ct) sacc[ct] = f32x4{0.f, 0.f, 0.f, 0.f};

#pragma unroll
        for (int ct = 0; ct < 4; ++ct) {
            const int rowb = (ct * 16 + lr) * 256;
#pragma unroll
            for (int c = 0; c < 4; ++c) {       // Khi slices
                const int g = c * 4 + hi8;
                const int slot = (g & 8) | ((g & 7) ^ kx);
                short8 kf = *(const short8*)&Ks[rowb + slot * 8];
                sacc[ct] = __builtin_amdgcn_mfma_f32_16x16x32_bf16(qf[c], kf, sacc[ct], 0, 0, 0);
                sacc[ct] = __builtin_amdgcn_mfma_f32_16x16x32_bf16(qf[4 + c], kf, sacc[ct], 0, 0, 0);
            }
#pragma unroll
            for (int c = 0; c < 4; ++c) {       // Klo slices (x Qhi)
                const int g = c * 4 + hi8;
                const int slot = 16 | (g & 8) | ((g & 7) ^ kx);
                short8 kf = *(const short8*)&Ks[rowb + slot * 8];
                sacc[ct] = __builtin_amdgcn_mfma_f32_16x16x32_bf16(qf[c], kf, sacc[ct], 0, 0, 0);
            }
        }

        // ---- online softmax (rows hi8*4+r) ----
        float scl[4];
#pragma unroll
        for (int r = 0; r < 4; ++r) {
            float tm = fmaxf(fmaxf(sacc[0][r], sacc[1][r]), fmaxf(sacc[2][r], sacc[3][r]));
            tm = fmaxf(tm, __shfl_xor(tm, 1));
            tm = fmaxf(tm, __shfl_xor(tm, 2));
            tm = fmaxf(tm, __shfl_xor(tm, 4));
            tm = fmaxf(tm, __shfl_xor(tm, 8));
            const float mnew = fmaxf(mrun[r], tm);
            const float sc = __expf(mrun[r] - mnew);
            float pv[4], ps = 0.f;
#pragma unroll
            for (int ct = 0; ct < 4; ++ct) {
                pv[ct] = __expf(sacc[ct][r] - mnew);
                ps += pv[ct];
            }
            ps += __shfl_xor(ps, 1); ps += __shfl_xor(ps, 2);
            ps += __shfl_xor(ps, 4); ps += __shfl_xor(ps, 8);
            lrun[r] = lrun[r] * sc + ps;
            mrun[r] = mnew;
            scl[r] = sc;
#pragma unroll
            for (int ct = 0; ct < 4; ++ct)
                Pw[(hi8 * 4 + r) * 72 + ct * 16 + lr] = f2bf(pv[ct]);
        }
#pragma unroll
        for (int dt = 0; dt < 8; ++dt)
#pragma unroll
            for (int r = 0; r < 4; ++r) acco[dt][r] *= scl[r];

        // ---- PV (plain bf16) ----
        short8 pf0 = *(const short8*)&Pw[lr * 72 + hi8 * 8];
        short8 pf1 = *(const short8*)&Pw[lr * 72 + 32 + hi8 * 8];
#pragma unroll
        for (int dt = 0; dt < 8; ++dt) {
            const int rowb = (dt * 16 + lr) * 64;
            short8 vf0 = *(const short8*)&Vs[rowb + ((0 + hi8) ^ kx) * 8];
            short8 vf1 = *(const short8*)&Vs[rowb + ((4 + hi8) ^ kx) * 8];
            acco[dt] = __builtin_amdgcn_mfma_f32_16x16x32_bf16(pf0, vf0, acco[dt], 0, 0, 0);
            acco[dt] = __builtin_amdgcn_mfma_f32_16x16x32_bf16(pf1, vf1, acco[dt], 0, 0, 0);
        }
        __syncthreads();   // all waves done reading before next stage overwrites
    }

    // epilogue: normalize, write hi-only output row
#pragma unroll
    for (int dt = 0; dt < 8; ++dt) {
        const int n = h * 128 + dt * 16 + lr;
#pragma unroll
        for (int r = 0; r < 4; ++r) {
            const int srow = qt * 64 + w * 16 + hi8 * 4 + r;
            A2[(size_t)srow * 4096 + n] = f2bf(acco[dt][r] / lrun[r]);
        }
    }
}

// ---------------------------------------------------------------------------
// launch
// ---------------------------------------------------------------------------
extern "C" void kernel_launch(void* const* d_in, const int* in_sizes, int n_in,
                              void* d_out, int out_size, void* d_ws, size_t ws_size,
                              hipStream_t stream)
{
    const float* x    = (const float*)d_in[0];
    const float* Wqkv = (const float*)d_in[1];
    const float* bqkv = (const float*)d_in[2];
    const float* Wo   = (const float*)d_in[3];
    const float* bo   = (const float*)d_in[4];
    const int*   pid  = (const int*)d_in[5];
    float* out = (float*)d_out;
    char* ws = (char*)d_ws;

    // workspace layout (byte offsets, peak 112 MB):
    //  [0,16M)   x2 ......... then Wo2t (after GEMM1)
    //  [16M,64M) Wq2t ....... then Q2 [16,32) K2 [32,48) Vt [48,56) A2 [56,72)
    //  [64M,112M) qkv fp32 .. dead after rope+tv (A2 tail overlaps it)
    const size_t MB = 1u << 20;
    unsigned short* x2   = (unsigned short*)(ws);
    unsigned short* Wq2t = (unsigned short*)(ws + 16 * MB);
    float*          qkv  = (float*)(ws + 64 * MB);
    unsigned short* Q2   = (unsigned short*)(ws + 16 * MB);
    unsigned short* K2   = (unsigned short*)(ws + 32 * MB);
    unsigned short* Vtb  = (unsigned short*)(ws + 48 * MB);
    unsigned short* Wo2t = (unsigned short*)(ws);
    unsigned short* A2   = (unsigned short*)(ws + 56 * MB);

    conv_x_kernel<<<4096, 256, 0, stream>>>(x, x2);
    tw_kernel<<<dim3(96, 32), 256, 0, stream>>>(Wqkv, Wq2t, 6144);
    // QKV projection: 3-term for Q/K columns (bx<32), 1-term (plain bf16) for V
    gemm_split_kernel<<<768, 256, 0, stream>>>(x2, Wq2t, bqkv, qkv, 6144, 48, 768, 32, 3, 1);
    rope_kernel<<<2048, 256, 0, stream>>>(qkv, pid, Q2, K2);
    tv_kernel<<<dim3(32, 32), 256, 0, stream>>>(qkv, Vtb);
    tw_kernel<<<dim3(32, 32), 256, 0, stream>>>(Wo, Wo2t, 2048);

    // flash attention: 512 blocks (16h x 32 q-tiles), 2 blocks/CU
    attn_kernel<<<512, 256, 0, stream>>>(Q2, K2, Vtb, A2);

    // output projection: 2-term (Ah*Bh + Ah*Bl); A-lo never read
    gemm_split_kernel<<<256, 256, 0, stream>>>(A2, Wo2t, bo, out, 2048, 16, 256, 16, 2, 2);
}

// Round 8
// 406.573 us; speedup vs baseline: 4.2248x; 1.1860x over previous
//
#include <hip/hip_runtime.h>
#include <cmath>

typedef __attribute__((ext_vector_type(8))) _Float16 half8;
typedef __attribute__((ext_vector_type(4))) float f32x4;

#define S_LEN 2048
#define DM    2048

__device__ __forceinline__ unsigned short h2u(_Float16 h) {
    union { _Float16 h; unsigned short u; } c; c.h = h; return c.u;
}
__device__ __forceinline__ void gload16(const void* g, void* l) {
    __builtin_amdgcn_global_load_lds(
        (const __attribute__((address_space(1))) unsigned*)g,
        (__attribute__((address_space(3))) unsigned*)l, 16, 0, 0);
}

// ---------------------------------------------------------------------------
// x [2048][2048] fp32 -> xh [2048][2048] f16 (hi only; lo side never needed)
// ---------------------------------------------------------------------------
__global__ __launch_bounds__(256) void conv_x_kernel(
    const float* __restrict__ x, _Float16* __restrict__ xh)
{
    const int idx = blockIdx.x * 256 + threadIdx.x;  // 8 floats each
    const int r = idx >> 8;
    const int c = (idx & 255) << 3;
    float4 v0 = *(const float4*)(x + (size_t)r * 2048 + c);
    float4 v1 = *(const float4*)(x + (size_t)r * 2048 + c + 4);
    unsigned short o[8];
    o[0] = h2u((_Float16)v0.x); o[1] = h2u((_Float16)v0.y);
    o[2] = h2u((_Float16)v0.z); o[3] = h2u((_Float16)v0.w);
    o[4] = h2u((_Float16)v1.x); o[5] = h2u((_Float16)v1.y);
    o[6] = h2u((_Float16)v1.z); o[7] = h2u((_Float16)v1.w);
    *(uint4*)((unsigned short*)xh + (size_t)r * 2048 + c) =
        make_uint4((unsigned)o[0] | ((unsigned)o[1] << 16),
                   (unsigned)o[2] | ((unsigned)o[3] << 16),
                   (unsigned)o[4] | ((unsigned)o[5] << 16),
                   (unsigned)o[6] | ((unsigned)o[7] << 16));
}

// ---------------------------------------------------------------------------
// W fp32 [2048][N] -> Wt [N][4096] f16: Wt[n][k]=hi(W[k][n]), [n][2048+k]=lo
// ---------------------------------------------------------------------------
__global__ __launch_bounds__(256) void tw_kernel(
    const float* __restrict__ W, _Float16* __restrict__ Wt, int N)
{
    __shared__ float T[64][65];
    const int t = threadIdx.x;
    const int bx = blockIdx.x;   // n block
    const int by = blockIdx.y;   // k block (32)
    {
        const int c = (t & 15) * 4;
        const int r0 = t >> 4;
#pragma unroll
        for (int i = 0; i < 4; ++i) {
            const int r = r0 + i * 16;
            float4 v = *(const float4*)(W + (size_t)(by * 64 + r) * N + bx * 64 + c);
            T[r][c] = v.x; T[r][c + 1] = v.y; T[r][c + 2] = v.z; T[r][c + 3] = v.w;
        }
    }
    __syncthreads();
    const int n = t >> 2;
    const int kq = (t & 3) * 16;
    unsigned hp[8], lp[8];
#pragma unroll
    for (int j = 0; j < 16; j += 2) {
        float f0 = T[kq + j][n], f1 = T[kq + j + 1][n];
        _Float16 a0 = (_Float16)f0, a1 = (_Float16)f1;
        _Float16 b0 = (_Float16)(f0 - (float)a0), b1 = (_Float16)(f1 - (float)a1);
        hp[j >> 1] = (unsigned)h2u(a0) | ((unsigned)h2u(a1) << 16);
        lp[j >> 1] = (unsigned)h2u(b0) | ((unsigned)h2u(b1) << 16);
    }
    unsigned short* dst = (unsigned short*)Wt + (size_t)(bx * 64 + n) * 4096 + by * 64 + kq;
    *(uint4*)(dst)            = make_uint4(hp[0], hp[1], hp[2], hp[3]);
    *(uint4*)(dst + 8)        = make_uint4(hp[4], hp[5], hp[6], hp[7]);
    *(uint4*)(dst + 2048)     = make_uint4(lp[0], lp[1], lp[2], lp[3]);
    *(uint4*)(dst + 2048 + 8) = make_uint4(lp[4], lp[5], lp[6], lp[7]);
}

// ---------------------------------------------------------------------------
// f16 2-term GEMM: C = Ah @ (Bhi [+ Blo]) + bias.
// A [M][strideA=2048] f16 (hi only); B2t [N][4096] f16 ([Bhi|Blo], K-major).
// term t uses B offset t*2048; A offset always 0.
// nt = (bx < nbx3) ? nt_lo : nt_hi.
// 128x128 tile, BK=64, 4 waves, global_load_lds w=16, XOR granule swizzle.
// ---------------------------------------------------------------------------
__global__ __launch_bounds__(256, 2) void gemm_split_kernel(
    const _Float16* __restrict__ A, const _Float16* __restrict__ B2t,
    const float* __restrict__ bias, float* __restrict__ C, int N, int strideA,
    int nbx, int nwg, int nbx3, int nt_lo, int nt_hi)
{
    __shared__ _Float16 As[128 * 64];
    __shared__ _Float16 Bs[128 * 64];
    const int wk = ((blockIdx.x & 7) * (nwg >> 3)) + (blockIdx.x >> 3);  // XCD swizzle
    const int bx = wk % nbx, by = wk / nbx;
    const int tid = threadIdx.x;
    const int lane = tid & 63, wv = tid >> 6;
    const int lr = lane & 15, hi8 = lane >> 4, kx = lane & 7;
    const int wm = wv >> 1, wn = wv & 1;
    const int nt = (bx < nbx3) ? nt_lo : nt_hi;

    f32x4 acc[4][4];
#pragma unroll
    for (int i = 0; i < 4; ++i)
#pragma unroll
        for (int j = 0; j < 4; ++j) acc[i][j] = f32x4{0.f, 0.f, 0.f, 0.f};

    int ldso[4]; size_t goffA[4]; size_t goffB[4];
#pragma unroll
    for (int i = 0; i < 4; ++i) {
        const int gr = i * 256 + tid;        // 16B granule id (1024 per tile)
        const int rr = gr >> 3, ss = gr & 7;
        const int gg = ss ^ (rr & 7);        // inverse swizzle on source
        ldso[i] = gr * 8;
        goffA[i] = (size_t)rr * strideA + gg * 8;
        goffB[i] = (size_t)rr * 4096 + gg * 8;
    }

    const _Float16* Abase = A + (size_t)by * 128 * strideA;
    const _Float16* Bbase = B2t + (size_t)bx * 128 * 4096;

    for (int term = 0; term < nt; ++term) {
        const _Float16* Ag = Abase;
        const _Float16* Bg = Bbase + term * 2048;
        for (int s32 = 0; s32 < 32; ++s32) {
#pragma unroll
            for (int i = 0; i < 4; ++i) gload16(Ag + goffA[i], &As[ldso[i]]);
#pragma unroll
            for (int i = 0; i < 4; ++i) gload16(Bg + goffB[i], &Bs[ldso[i]]);
            __syncthreads();   // compiler drains vmcnt here -> tiles ready
#pragma unroll
            for (int kc = 0; kc < 2; ++kc) {
                const int slot8 = ((kc * 4 + hi8) ^ kx) * 8;
                half8 aF[4], bF[4];
#pragma unroll
                for (int mt = 0; mt < 4; ++mt)
                    aF[mt] = *(const half8*)&As[(wm * 64 + mt * 16 + lr) * 64 + slot8];
#pragma unroll
                for (int nt2 = 0; nt2 < 4; ++nt2)
                    bF[nt2] = *(const half8*)&Bs[(wn * 64 + nt2 * 16 + lr) * 64 + slot8];
#pragma unroll
                for (int mt = 0; mt < 4; ++mt)
#pragma unroll
                    for (int nt2 = 0; nt2 < 4; ++nt2)
                        acc[mt][nt2] = __builtin_amdgcn_mfma_f32_16x16x32_f16(
                            aF[mt], bF[nt2], acc[mt][nt2], 0, 0, 0);
            }
            __syncthreads();   // all reads done before next overwrite
            Ag += 64; Bg += 64;
        }
    }

#pragma unroll
    for (int nt2 = 0; nt2 < 4; ++nt2) {
        const int col = bx * 128 + wn * 64 + nt2 * 16 + lr;
        const float bv = bias[col];
#pragma unroll
        for (int mt = 0; mt < 4; ++mt)
#pragma unroll
            for (int r = 0; r < 4; ++r) {
                const int row = by * 128 + wm * 64 + mt * 16 + hi8 * 4 + r;
                C[(size_t)row * N + col] = acc[mt][nt2][r] + bv;
            }
    }
}

// ---------------------------------------------------------------------------
// Dual RoPE (fp32 math): qkv [S][6144] -> Q2 [H][S][128] f16 (hi only),
// K2 [H][S][256] f16 ([hi(128)|lo(128)])
// ---------------------------------------------------------------------------
__global__ __launch_bounds__(256) void rope_kernel(
    const float* __restrict__ qkv, const int* __restrict__ pid,
    _Float16* __restrict__ Q2, _Float16* __restrict__ K2)
{
    const int s = blockIdx.x, t = threadIdx.x;
    const int h = t >> 4, rem = t & 15, b = rem >> 3, e4 = (rem & 7) * 4;
    const size_t rb = (size_t)s * 6144;
    const int cq = h * 128 + b * 64 + e4;

    float4 q1 = *(const float4*)(qkv + rb + cq);
    float4 q2v = *(const float4*)(qkv + rb + cq + 32);
    float4 k1 = *(const float4*)(qkv + rb + 2048 + cq);
    float4 k2v = *(const float4*)(qkv + rb + 2048 + cq + 32);
    const float pos = (float)((b == 0) ? pid[s] : pid[2048 + s]);

    float qa[4] = {q1.x, q1.y, q1.z, q1.w};
    float qb[4] = {q2v.x, q2v.y, q2v.z, q2v.w};
    float ka[4] = {k1.x, k1.y, k1.z, k1.w};
    float kb[4] = {k2v.x, k2v.y, k2v.z, k2v.w};
    float qo1[4], qo2[4], ko1[4], ko2[4];
#pragma unroll
    for (int u = 0; u < 4; ++u) {
        const float j = (float)(e4 + u);
        const float invf = powf(10000.f, -j * (1.f / 32.f));
        const float ang = pos * invf;
        float sn, cs;
        sincosf(ang, &sn, &cs);
        qo1[u] = qa[u] * cs - qb[u] * sn;
        qo2[u] = qb[u] * cs + qa[u] * sn;
        ko1[u] = ka[u] * cs - kb[u] * sn;
        ko2[u] = kb[u] * cs + ka[u] * sn;
    }

    // Q: hi only
    unsigned short* qd = (unsigned short*)Q2 + ((size_t)h * 2048 + s) * 128 + b * 64 + e4;
    *(ushort4*)(qd) = make_ushort4(h2u((_Float16)qo1[0]), h2u((_Float16)qo1[1]),
                                   h2u((_Float16)qo1[2]), h2u((_Float16)qo1[3]));
    *(ushort4*)(qd + 32) = make_ushort4(h2u((_Float16)qo2[0]), h2u((_Float16)qo2[1]),
                                        h2u((_Float16)qo2[2]), h2u((_Float16)qo2[3]));
    // K: hi + lo
    unsigned short* kd = (unsigned short*)K2 + ((size_t)h * 2048 + s) * 256 + b * 64 + e4;
    unsigned short hh[8], ll[8];
#pragma unroll
    for (int u = 0; u < 4; ++u) {
        _Float16 h1 = (_Float16)ko1[u];
        _Float16 h2v = (_Float16)ko2[u];
        hh[u] = h2u(h1);      ll[u] = h2u((_Float16)(ko1[u] - (float)h1));
        hh[4 + u] = h2u(h2v); ll[4 + u] = h2u((_Float16)(ko2[u] - (float)h2v));
    }
    *(ushort4*)(kd)       = make_ushort4(hh[0], hh[1], hh[2], hh[3]);
    *(ushort4*)(kd + 32)  = make_ushort4(hh[4], hh[5], hh[6], hh[7]);
    *(ushort4*)(kd + 128) = make_ushort4(ll[0], ll[1], ll[2], ll[3]);
    *(ushort4*)(kd + 160) = make_ushort4(ll[4], ll[5], ll[6], ll[7]);
}

// ---------------------------------------------------------------------------
// V transpose: qkv cols [4096,6144) fp32 -> Vt [H][128][S] f16
// ---------------------------------------------------------------------------
__global__ __launch_bounds__(256) void tv_kernel(
    const float* __restrict__ qkv, _Float16* __restrict__ Vt)
{
    __shared__ float T[64][65];
    const int t = threadIdx.x;
    const int bs = blockIdx.x;   // s block (32)
    const int bc = blockIdx.y;   // v-col block (32)
    {
        const int c = (t & 15) * 4;
        const int r0 = t >> 4;
#pragma unroll
        for (int i = 0; i < 4; ++i) {
            const int r = r0 + i * 16;
            float4 v = *(const float4*)(qkv + (size_t)(bs * 64 + r) * 6144 + 4096 + bc * 64 + c);
            T[r][c] = v.x; T[r][c + 1] = v.y; T[r][c + 2] = v.z; T[r][c + 3] = v.w;
        }
    }
    __syncthreads();
    const int d = t >> 2;
    const int sq = (t & 3) * 16;
    const int gcol = bc * 64 + d;
    const int h = gcol >> 7, dd = gcol & 127;
    unsigned hp[8];
#pragma unroll
    for (int j = 0; j < 16; j += 2) {
        hp[j >> 1] = (unsigned)h2u((_Float16)T[sq + j][d]) |
                     ((unsigned)h2u((_Float16)T[sq + j + 1][d]) << 16);
    }
    unsigned short* dst = (unsigned short*)Vt + ((size_t)h * 128 + dd) * 2048 + bs * 64 + sq;
    *(uint4*)(dst)     = make_uint4(hp[0], hp[1], hp[2], hp[3]);
    *(uint4*)(dst + 8) = make_uint4(hp[4], hp[5], hp[6], hp[7]);
}

// ---------------------------------------------------------------------------
// MFMA flash attention v4 (f16 2-term). 512 blocks = 16 heads x 32 q-tiles
// (64 rows), 2 blocks/CU (58 KB LDS), 4 waves x 16 q-rows.
// QK^T = Qhi*(Khi+Klo); softmax fp32; PV plain f16. Q hoisted (4 frags).
// ---------------------------------------------------------------------------
__global__ __launch_bounds__(256, 2) void attn_kernel(
    const _Float16* __restrict__ Q2, const _Float16* __restrict__ K2,
    const _Float16* __restrict__ Vt, _Float16* __restrict__ A2)
{
    __shared__ _Float16 Ks[64 * 256];    // 32 KB
    __shared__ _Float16 Vs[128 * 64];    // 16 KB
    __shared__ _Float16 Ps[4 * 16 * 72]; //  9 KB

    const int bid = blockIdx.x;
    const int idx = bid >> 3;
    const int h = ((bid & 7) << 1) | (idx >> 5);   // 2 heads per XCD
    const int qt = idx & 31;                       // 64-row q tile
    const int tid = threadIdx.x;
    const int w = tid >> 6, lane = tid & 63;
    const int lr = lane & 15, hi8 = lane >> 4, kx = lane & 7;

    // Q fragments (hi only) for this wave's 16 rows
    half8 qf[4];
    {
        const _Float16* Qr = Q2 + ((size_t)h * 2048 + qt * 64 + w * 16 + lr) * 128;
#pragma unroll
        for (int c = 0; c < 4; ++c)
            qf[c] = *(const half8*)(Qr + c * 32 + hi8 * 8);
    }

    f32x4 acco[8];
    float mrun[4], lrun[4];
#pragma unroll
    for (int i = 0; i < 8; ++i) acco[i] = f32x4{0.f, 0.f, 0.f, 0.f};
#pragma unroll
    for (int r = 0; r < 4; ++r) { mrun[r] = -INFINITY; lrun[r] = 0.f; }

    // staging offset tables (pre-swizzled global source, linear LDS dest)
    int kl[8], kg[8];
#pragma unroll
    for (int i = 0; i < 8; ++i) {
        const int gr = i * 256 + tid;
        const int rr = gr >> 5, ss = gr & 31;
        const int gg = (ss & 24) | ((ss & 7) ^ (rr & 7));
        kl[i] = gr * 8;
        kg[i] = rr * 256 + gg * 8;
    }
    int vl[4], vg[4];
#pragma unroll
    for (int i = 0; i < 4; ++i) {
        const int gr = i * 256 + tid;
        const int rr = gr >> 3, ss = gr & 7;
        const int gg = ss ^ (rr & 7);
        vl[i] = gr * 8;
        vg[i] = rr * 2048 + gg * 8;
    }

    const _Float16* Kh = K2 + (size_t)h * 2048 * 256;
    const _Float16* Vh = Vt + (size_t)h * 128 * 2048;
    _Float16* Pw = Ps + w * 16 * 72;

    for (int kt = 0; kt < 32; ++kt) {
        // stage K,V tile (async); barrier drains vmcnt -> data ready
        {
            const _Float16* Kg = Kh + (size_t)kt * 16384;
            const _Float16* Vg = Vh + kt * 64;
#pragma unroll
            for (int i = 0; i < 8; ++i) gload16(Kg + kg[i], &Ks[kl[i]]);
#pragma unroll
            for (int i = 0; i < 4; ++i) gload16(Vg + vg[i], &Vs[vl[i]]);
        }
        __syncthreads();

        // ---- QK^T: Qhi*(Khi + Klo) ----
        f32x4 sacc[4];
#pragma unroll
        for (int ct = 0; ct < 4; ++ct) sacc[ct] = f32x4{0.f, 0.f, 0.f, 0.f};

#pragma unroll
        for (int ct = 0; ct < 4; ++ct) {
            const int rowb = (ct * 16 + lr) * 256;
#pragma unroll
            for (int c = 0; c < 4; ++c) {       // Khi slices
                const int g = c * 4 + hi8;
                const int slot = (g & 8) | ((g & 7) ^ kx);
                half8 kf = *(const half8*)&Ks[rowb + slot * 8];
                sacc[ct] = __builtin_amdgcn_mfma_f32_16x16x32_f16(qf[c], kf, sacc[ct], 0, 0, 0);
            }
#pragma unroll
            for (int c = 0; c < 4; ++c) {       // Klo slices
                const int g = c * 4 + hi8;
                const int slot = 16 | (g & 8) | ((g & 7) ^ kx);
                half8 kf = *(const half8*)&Ks[rowb + slot * 8];
                sacc[ct] = __builtin_amdgcn_mfma_f32_16x16x32_f16(qf[c], kf, sacc[ct], 0, 0, 0);
            }
        }

        // ---- online softmax (rows hi8*4+r) ----
        float scl[4];
#pragma unroll
        for (int r = 0; r < 4; ++r) {
            float tm = fmaxf(fmaxf(sacc[0][r], sacc[1][r]), fmaxf(sacc[2][r], sacc[3][r]));
            tm = fmaxf(tm, __shfl_xor(tm, 1));
            tm = fmaxf(tm, __shfl_xor(tm, 2));
            tm = fmaxf(tm, __shfl_xor(tm, 4));
            tm = fmaxf(tm, __shfl_xor(tm, 8));
            const float mnew = fmaxf(mrun[r], tm);
            const float sc = __expf(mrun[r] - mnew);
            float pv[4], ps = 0.f;
#pragma unroll
            for (int ct = 0; ct < 4; ++ct) {
                pv[ct] = __expf(sacc[ct][r] - mnew);
                ps += pv[ct];
            }
            ps += __shfl_xor(ps, 1); ps += __shfl_xor(ps, 2);
            ps += __shfl_xor(ps, 4); ps += __shfl_xor(ps, 8);
            lrun[r] = lrun[r] * sc + ps;
            mrun[r] = mnew;
            scl[r] = sc;
#pragma unroll
            for (int ct = 0; ct < 4; ++ct)
                Pw[(hi8 * 4 + r) * 72 + ct * 16 + lr] = (_Float16)pv[ct];
        }
#pragma unroll
        for (int dt = 0; dt < 8; ++dt)
#pragma unroll
            for (int r = 0; r < 4; ++r) acco[dt][r] *= scl[r];

        // ---- PV (plain f16) ----
        half8 pf0 = *(const half8*)&Pw[lr * 72 + hi8 * 8];
        half8 pf1 = *(const half8*)&Pw[lr * 72 + 32 + hi8 * 8];
#pragma unroll
        for (int dt = 0; dt < 8; ++dt) {
            const int rowb = (dt * 16 + lr) * 64;
            half8 vf0 = *(const half8*)&Vs[rowb + ((0 + hi8) ^ kx) * 8];
            half8 vf1 = *(const half8*)&Vs[rowb + ((4 + hi8) ^ kx) * 8];
            acco[dt] = __builtin_amdgcn_mfma_f32_16x16x32_f16(pf0, vf0, acco[dt], 0, 0, 0);
            acco[dt] = __builtin_amdgcn_mfma_f32_16x16x32_f16(pf1, vf1, acco[dt], 0, 0, 0);
        }
        __syncthreads();   // all waves done reading before next stage overwrites
    }

    // epilogue: normalize, write f16 output row [S][2048]
#pragma unroll
    for (int dt = 0; dt < 8; ++dt) {
        const int n = h * 128 + dt * 16 + lr;
#pragma unroll
        for (int r = 0; r < 4; ++r) {
            const int srow = qt * 64 + w * 16 + hi8 * 4 + r;
            A2[(size_t)srow * 2048 + n] = (_Float16)(acco[dt][r] / lrun[r]);
        }
    }
}

// ---------------------------------------------------------------------------
// launch
// ---------------------------------------------------------------------------
extern "C" void kernel_launch(void* const* d_in, const int* in_sizes, int n_in,
                              void* d_out, int out_size, void* d_ws, size_t ws_size,
                              hipStream_t stream)
{
    const float* x    = (const float*)d_in[0];
    const float* Wqkv = (const float*)d_in[1];
    const float* bqkv = (const float*)d_in[2];
    const float* Wo   = (const float*)d_in[3];
    const float* bo   = (const float*)d_in[4];
    const int*   pid  = (const int*)d_in[5];
    float* out = (float*)d_out;
    char* ws = (char*)d_ws;

    // workspace layout (byte offsets, peak 112 MB):
    //  [0,8M)    xh (f16 hi) ..... then Wo2t [0,16M) (after GEMM1)
    //  [16M,64M) Wq2t ............ then Q2 [16,24) K2 [32,48) Vt [48,56) A2 [56,64)
    //  [64M,112M) qkv fp32 ....... dead after rope+tv
    const size_t MB = 1u << 20;
    _Float16* xh   = (_Float16*)(ws);
    _Float16* Wq2t = (_Float16*)(ws + 16 * MB);
    float*    qkv  = (float*)(ws + 64 * MB);
    _Float16* Q2   = (_Float16*)(ws + 16 * MB);
    _Float16* K2   = (_Float16*)(ws + 32 * MB);
    _Float16* Vtb  = (_Float16*)(ws + 48 * MB);
    _Float16* Wo2t = (_Float16*)(ws);
    _Float16* A2   = (_Float16*)(ws + 56 * MB);

    conv_x_kernel<<<2048, 256, 0, stream>>>(x, xh);
    tw_kernel<<<dim3(96, 32), 256, 0, stream>>>(Wqkv, Wq2t, 6144);
    // QKV projection: 2-term for Q/K columns (bx<32), 1-term for V
    gemm_split_kernel<<<768, 256, 0, stream>>>(xh, Wq2t, bqkv, qkv, 6144, 2048, 48, 768, 32, 2, 1);
    rope_kernel<<<2048, 256, 0, stream>>>(qkv, pid, Q2, K2);
    tv_kernel<<<dim3(32, 32), 256, 0, stream>>>(qkv, Vtb);
    tw_kernel<<<dim3(32, 32), 256, 0, stream>>>(Wo, Wo2t, 2048);

    // flash attention: 512 blocks (16h x 32 q-tiles), 2 blocks/CU
    attn_kernel<<<512, 256, 0, stream>>>(Q2, K2, Vtb, A2);

    // output projection: 2-term (Ah*Bh + Ah*Bl)
    gemm_split_kernel<<<256, 256, 0, stream>>>(A2, Wo2t, bo, out, 2048, 2048, 16, 256, 16, 2, 2);
}

// Round 9
// 372.484 us; speedup vs baseline: 4.6114x; 1.0915x over previous
//
#include <hip/hip_runtime.h>
#include <cmath>

typedef __attribute__((ext_vector_type(8))) _Float16 half8;
typedef __attribute__((ext_vector_type(4))) float f32x4;

#define S_LEN 2048
#define DM    2048

__device__ __forceinline__ unsigned short h2u(_Float16 h) {
    union { _Float16 h; unsigned short u; } c; c.h = h; return c.u;
}
__device__ __forceinline__ void gload16(const void* g, void* l) {
    __builtin_amdgcn_global_load_lds(
        (const __attribute__((address_space(1))) unsigned*)g,
        (__attribute__((address_space(3))) unsigned*)l, 16, 0, 0);
}

// ---------------------------------------------------------------------------
// x [2048][2048] fp32 -> xh [2048][2048] f16 (hi only)
// ---------------------------------------------------------------------------
__global__ __launch_bounds__(256) void conv_x_kernel(
    const float* __restrict__ x, _Float16* __restrict__ xh)
{
    const int idx = blockIdx.x * 256 + threadIdx.x;  // 8 floats each
    const int r = idx >> 8;
    const int c = (idx & 255) << 3;
    float4 v0 = *(const float4*)(x + (size_t)r * 2048 + c);
    float4 v1 = *(const float4*)(x + (size_t)r * 2048 + c + 4);
    unsigned short o[8];
    o[0] = h2u((_Float16)v0.x); o[1] = h2u((_Float16)v0.y);
    o[2] = h2u((_Float16)v0.z); o[3] = h2u((_Float16)v0.w);
    o[4] = h2u((_Float16)v1.x); o[5] = h2u((_Float16)v1.y);
    o[6] = h2u((_Float16)v1.z); o[7] = h2u((_Float16)v1.w);
    *(uint4*)((unsigned short*)xh + (size_t)r * 2048 + c) =
        make_uint4((unsigned)o[0] | ((unsigned)o[1] << 16),
                   (unsigned)o[2] | ((unsigned)o[3] << 16),
                   (unsigned)o[4] | ((unsigned)o[5] << 16),
                   (unsigned)o[6] | ((unsigned)o[7] << 16));
}

// ---------------------------------------------------------------------------
// W fp32 [2048][N] -> Wt [N][4096] f16: Wt[n][k]=hi(W[k][n]), [n][2048+k]=lo
// ---------------------------------------------------------------------------
__global__ __launch_bounds__(256) void tw_kernel(
    const float* __restrict__ W, _Float16* __restrict__ Wt, int N)
{
    __shared__ float T[64][65];
    const int t = threadIdx.x;
    const int bx = blockIdx.x;   // n block
    const int by = blockIdx.y;   // k block (32)
    {
        const int c = (t & 15) * 4;
        const int r0 = t >> 4;
#pragma unroll
        for (int i = 0; i < 4; ++i) {
            const int r = r0 + i * 16;
            float4 v = *(const float4*)(W + (size_t)(by * 64 + r) * N + bx * 64 + c);
            T[r][c] = v.x; T[r][c + 1] = v.y; T[r][c + 2] = v.z; T[r][c + 3] = v.w;
        }
    }
    __syncthreads();
    const int n = t >> 2;
    const int kq = (t & 3) * 16;
    unsigned hp[8], lp[8];
#pragma unroll
    for (int j = 0; j < 16; j += 2) {
        float f0 = T[kq + j][n], f1 = T[kq + j + 1][n];
        _Float16 a0 = (_Float16)f0, a1 = (_Float16)f1;
        _Float16 b0 = (_Float16)(f0 - (float)a0), b1 = (_Float16)(f1 - (float)a1);
        hp[j >> 1] = (unsigned)h2u(a0) | ((unsigned)h2u(a1) << 16);
        lp[j >> 1] = (unsigned)h2u(b0) | ((unsigned)h2u(b1) << 16);
    }
    unsigned short* dst = (unsigned short*)Wt + (size_t)(bx * 64 + n) * 4096 + by * 64 + kq;
    *(uint4*)(dst)            = make_uint4(hp[0], hp[1], hp[2], hp[3]);
    *(uint4*)(dst + 8)        = make_uint4(hp[4], hp[5], hp[6], hp[7]);
    *(uint4*)(dst + 2048)     = make_uint4(lp[0], lp[1], lp[2], lp[3]);
    *(uint4*)(dst + 2048 + 8) = make_uint4(lp[4], lp[5], lp[6], lp[7]);
}

// ---------------------------------------------------------------------------
// f16 fused 2-term GEMM: C = Ah @ (Bhi [+ Blo]) + bias, single K pass.
// A staged once; Bhi and Blo staged into separate LDS buffers; 64 MFMA per
// barrier pair (vs 32) -> amortizes the barrier drain.
// nt = (bx < nbx3) ? nt_lo : nt_hi (1 or 2).
// ---------------------------------------------------------------------------
__global__ __launch_bounds__(256, 2) void gemm_split_kernel(
    const _Float16* __restrict__ A, const _Float16* __restrict__ B2t,
    const float* __restrict__ bias, float* __restrict__ C, int N, int strideA,
    int nbx, int nwg, int nbx3, int nt_lo, int nt_hi)
{
    __shared__ _Float16 As[128 * 64];
    __shared__ _Float16 Bs[128 * 64];
    __shared__ _Float16 Bs2[128 * 64];
    const int wk = ((blockIdx.x & 7) * (nwg >> 3)) + (blockIdx.x >> 3);  // XCD swizzle
    const int bx = wk % nbx, by = wk / nbx;
    const int tid = threadIdx.x;
    const int lane = tid & 63, wv = tid >> 6;
    const int lr = lane & 15, hi8 = lane >> 4, kx = lane & 7;
    const int wm = wv >> 1, wn = wv & 1;
    const int nt = (bx < nbx3) ? nt_lo : nt_hi;

    f32x4 acc[4][4];
#pragma unroll
    for (int i = 0; i < 4; ++i)
#pragma unroll
        for (int j = 0; j < 4; ++j) acc[i][j] = f32x4{0.f, 0.f, 0.f, 0.f};

    int ldso[4]; size_t goffA[4]; size_t goffB[4];
#pragma unroll
    for (int i = 0; i < 4; ++i) {
        const int gr = i * 256 + tid;        // 16B granule id (1024 per tile)
        const int rr = gr >> 3, ss = gr & 7;
        const int gg = ss ^ (rr & 7);        // inverse swizzle on source
        ldso[i] = gr * 8;
        goffA[i] = (size_t)rr * strideA + gg * 8;
        goffB[i] = (size_t)rr * 4096 + gg * 8;
    }

    const _Float16* Ag = A + (size_t)by * 128 * strideA;
    const _Float16* Bg = B2t + (size_t)bx * 128 * 4096;

    for (int s32 = 0; s32 < 32; ++s32) {
#pragma unroll
        for (int i = 0; i < 4; ++i) gload16(Ag + goffA[i], &As[ldso[i]]);
#pragma unroll
        for (int i = 0; i < 4; ++i) gload16(Bg + goffB[i], &Bs[ldso[i]]);
        if (nt == 2) {
#pragma unroll
            for (int i = 0; i < 4; ++i) gload16(Bg + 2048 + goffB[i], &Bs2[ldso[i]]);
        }
        __syncthreads();   // drains vmcnt -> tiles ready
#pragma unroll
        for (int kc = 0; kc < 2; ++kc) {
            const int slot8 = ((kc * 4 + hi8) ^ kx) * 8;
            half8 aF[4], bF[4];
#pragma unroll
            for (int mt = 0; mt < 4; ++mt)
                aF[mt] = *(const half8*)&As[(wm * 64 + mt * 16 + lr) * 64 + slot8];
#pragma unroll
            for (int nt2 = 0; nt2 < 4; ++nt2)
                bF[nt2] = *(const half8*)&Bs[(wn * 64 + nt2 * 16 + lr) * 64 + slot8];
#pragma unroll
            for (int mt = 0; mt < 4; ++mt)
#pragma unroll
                for (int nt2 = 0; nt2 < 4; ++nt2)
                    acc[mt][nt2] = __builtin_amdgcn_mfma_f32_16x16x32_f16(
                        aF[mt], bF[nt2], acc[mt][nt2], 0, 0, 0);
            if (nt == 2) {
#pragma unroll
                for (int nt2 = 0; nt2 < 4; ++nt2)
                    bF[nt2] = *(const half8*)&Bs2[(wn * 64 + nt2 * 16 + lr) * 64 + slot8];
#pragma unroll
                for (int mt = 0; mt < 4; ++mt)
#pragma unroll
                    for (int nt2 = 0; nt2 < 4; ++nt2)
                        acc[mt][nt2] = __builtin_amdgcn_mfma_f32_16x16x32_f16(
                            aF[mt], bF[nt2], acc[mt][nt2], 0, 0, 0);
            }
        }
        __syncthreads();   // all reads done before next overwrite
        Ag += 64; Bg += 64;
    }

#pragma unroll
    for (int nt2 = 0; nt2 < 4; ++nt2) {
        const int col = bx * 128 + wn * 64 + nt2 * 16 + lr;
        const float bv = bias[col];
#pragma unroll
        for (int mt = 0; mt < 4; ++mt)
#pragma unroll
            for (int r = 0; r < 4; ++r) {
                const int row = by * 128 + wm * 64 + mt * 16 + hi8 * 4 + r;
                C[(size_t)row * N + col] = acc[mt][nt2][r] + bv;
            }
    }
}

// ---------------------------------------------------------------------------
// Dual RoPE (fp32 math): qkv [S][6144] -> Q2 [H][S][128] f16 (hi only),
// K2 [H][S][256] f16 ([hi(128)|lo(128)])
// ---------------------------------------------------------------------------
__global__ __launch_bounds__(256) void rope_kernel(
    const float* __restrict__ qkv, const int* __restrict__ pid,
    _Float16* __restrict__ Q2, _Float16* __restrict__ K2)
{
    const int s = blockIdx.x, t = threadIdx.x;
    const int h = t >> 4, rem = t & 15, b = rem >> 3, e4 = (rem & 7) * 4;
    const size_t rb = (size_t)s * 6144;
    const int cq = h * 128 + b * 64 + e4;

    float4 q1 = *(const float4*)(qkv + rb + cq);
    float4 q2v = *(const float4*)(qkv + rb + cq + 32);
    float4 k1 = *(const float4*)(qkv + rb + 2048 + cq);
    float4 k2v = *(const float4*)(qkv + rb + 2048 + cq + 32);
    const float pos = (float)((b == 0) ? pid[s] : pid[2048 + s]);

    float qa[4] = {q1.x, q1.y, q1.z, q1.w};
    float qb[4] = {q2v.x, q2v.y, q2v.z, q2v.w};
    float ka[4] = {k1.x, k1.y, k1.z, k1.w};
    float kb[4] = {k2v.x, k2v.y, k2v.z, k2v.w};
    float qo1[4], qo2[4], ko1[4], ko2[4];
#pragma unroll
    for (int u = 0; u < 4; ++u) {
        const float j = (float)(e4 + u);
        const float invf = powf(10000.f, -j * (1.f / 32.f));
        const float ang = pos * invf;
        float sn, cs;
        sincosf(ang, &sn, &cs);
        qo1[u] = qa[u] * cs - qb[u] * sn;
        qo2[u] = qb[u] * cs + qa[u] * sn;
        ko1[u] = ka[u] * cs - kb[u] * sn;
        ko2[u] = kb[u] * cs + ka[u] * sn;
    }

    // Q: hi only
    unsigned short* qd = (unsigned short*)Q2 + ((size_t)h * 2048 + s) * 128 + b * 64 + e4;
    *(ushort4*)(qd) = make_ushort4(h2u((_Float16)qo1[0]), h2u((_Float16)qo1[1]),
                                   h2u((_Float16)qo1[2]), h2u((_Float16)qo1[3]));
    *(ushort4*)(qd + 32) = make_ushort4(h2u((_Float16)qo2[0]), h2u((_Float16)qo2[1]),
                                        h2u((_Float16)qo2[2]), h2u((_Float16)qo2[3]));
    // K: hi + lo
    unsigned short* kd = (unsigned short*)K2 + ((size_t)h * 2048 + s) * 256 + b * 64 + e4;
    unsigned short hh[8], ll[8];
#pragma unroll
    for (int u = 0; u < 4; ++u) {
        _Float16 h1 = (_Float16)ko1[u];
        _Float16 h2v = (_Float16)ko2[u];
        hh[u] = h2u(h1);      ll[u] = h2u((_Float16)(ko1[u] - (float)h1));
        hh[4 + u] = h2u(h2v); ll[4 + u] = h2u((_Float16)(ko2[u] - (float)h2v));
    }
    *(ushort4*)(kd)       = make_ushort4(hh[0], hh[1], hh[2], hh[3]);
    *(ushort4*)(kd + 32)  = make_ushort4(hh[4], hh[5], hh[6], hh[7]);
    *(ushort4*)(kd + 128) = make_ushort4(ll[0], ll[1], ll[2], ll[3]);
    *(ushort4*)(kd + 160) = make_ushort4(ll[4], ll[5], ll[6], ll[7]);
}

// ---------------------------------------------------------------------------
// V transpose: qkv cols [4096,6144) fp32 -> Vt [H][128][S] f16
// ---------------------------------------------------------------------------
__global__ __launch_bounds__(256) void tv_kernel(
    const float* __restrict__ qkv, _Float16* __restrict__ Vt)
{
    __shared__ float T[64][65];
    const int t = threadIdx.x;
    const int bs = blockIdx.x;   // s block (32)
    const int bc = blockIdx.y;   // v-col block (32)
    {
        const int c = (t & 15) * 4;
        const int r0 = t >> 4;
#pragma unroll
        for (int i = 0; i < 4; ++i) {
            const int r = r0 + i * 16;
            float4 v = *(const float4*)(qkv + (size_t)(bs * 64 + r) * 6144 + 4096 + bc * 64 + c);
            T[r][c] = v.x; T[r][c + 1] = v.y; T[r][c + 2] = v.z; T[r][c + 3] = v.w;
        }
    }
    __syncthreads();
    const int d = t >> 2;
    const int sq = (t & 3) * 16;
    const int gcol = bc * 64 + d;
    const int h = gcol >> 7, dd = gcol & 127;
    unsigned hp[8];
#pragma unroll
    for (int j = 0; j < 16; j += 2) {
        hp[j >> 1] = (unsigned)h2u((_Float16)T[sq + j][d]) |
                     ((unsigned)h2u((_Float16)T[sq + j + 1][d]) << 16);
    }
    unsigned short* dst = (unsigned short*)Vt + ((size_t)h * 128 + dd) * 2048 + bs * 64 + sq;
    *(uint4*)(dst)     = make_uint4(hp[0], hp[1], hp[2], hp[3]);
    *(uint4*)(dst + 8) = make_uint4(hp[4], hp[5], hp[6], hp[7]);
}

// ---------------------------------------------------------------------------
// MFMA flash attention v5: swapped QK^T (mfma(K,Q)) -> lane holds a full
// 16-of-64 slice of ONE q-row's logits (q = lane&15). In-register softmax:
// in-lane tree + 2 shfl_xor(16/32); P written as 8 packed b32; rescale via
// 4-shfl gather. Same LDS layout/sizes as v4 (58 KB, 2 blocks/CU).
// ---------------------------------------------------------------------------
__global__ __launch_bounds__(256, 2) void attn_kernel(
    const _Float16* __restrict__ Q2, const _Float16* __restrict__ K2,
    const _Float16* __restrict__ Vt, _Float16* __restrict__ A2)
{
    __shared__ _Float16 Ks[64 * 256];    // 32 KB
    __shared__ _Float16 Vs[128 * 64];    // 16 KB
    __shared__ _Float16 Ps[4 * 16 * 72]; //  9 KB

    const int bid = blockIdx.x;
    const int idx = bid >> 3;
    const int h = ((bid & 7) << 1) | (idx >> 5);   // 2 heads per XCD
    const int qt = idx & 31;                       // 64-row q tile
    const int tid = threadIdx.x;
    const int w = tid >> 6, lane = tid & 63;
    const int lr = lane & 15, hi8 = lane >> 4, kx = lane & 7;

    // Q fragments (hi only) for this wave's 16 rows; row = lane&15 -> also the
    // B-operand (col=q) layout needed by swapped QK^T.
    half8 qf[4];
    {
        const _Float16* Qr = Q2 + ((size_t)h * 2048 + qt * 64 + w * 16 + lr) * 128;
#pragma unroll
        for (int c = 0; c < 4; ++c)
            qf[c] = *(const half8*)(Qr + c * 32 + hi8 * 8);
    }

    f32x4 acco[8];
    float mrun = -INFINITY, lrun = 0.f;   // stats for q = lane&15 (replicated over hi8)
#pragma unroll
    for (int i = 0; i < 8; ++i) acco[i] = f32x4{0.f, 0.f, 0.f, 0.f};

    // staging offset tables (pre-swizzled global source, linear LDS dest)
    int kl[8], kg[8];
#pragma unroll
    for (int i = 0; i < 8; ++i) {
        const int gr = i * 256 + tid;
        const int rr = gr >> 5, ss = gr & 31;
        const int gg = (ss & 24) | ((ss & 7) ^ (rr & 7));
        kl[i] = gr * 8;
        kg[i] = rr * 256 + gg * 8;
    }
    int vl[4], vg[4];
#pragma unroll
    for (int i = 0; i < 4; ++i) {
        const int gr = i * 256 + tid;
        const int rr = gr >> 3, ss = gr & 7;
        const int gg = ss ^ (rr & 7);
        vl[i] = gr * 8;
        vg[i] = rr * 2048 + gg * 8;
    }

    const _Float16* Kh = K2 + (size_t)h * 2048 * 256;
    const _Float16* Vh = Vt + (size_t)h * 128 * 2048;
    _Float16* Pw = Ps + w * 16 * 72;

    for (int kt = 0; kt < 32; ++kt) {
        // stage K,V tile (async); barrier drains vmcnt -> data ready
        {
            const _Float16* Kg = Kh + (size_t)kt * 16384;
            const _Float16* Vg = Vh + kt * 64;
#pragma unroll
            for (int i = 0; i < 8; ++i) gload16(Kg + kg[i], &Ks[kl[i]]);
#pragma unroll
            for (int i = 0; i < 4; ++i) gload16(Vg + vg[i], &Vs[vl[i]]);
        }
        __syncthreads();

        // ---- swapped QK^T: sacc[ct][r] = logits[q=lr][k=ct*16+hi8*4+r] ----
        f32x4 sacc[4];
#pragma unroll
        for (int ct = 0; ct < 4; ++ct) sacc[ct] = f32x4{0.f, 0.f, 0.f, 0.f};

#pragma unroll
        for (int ct = 0; ct < 4; ++ct) {
            const int rowb = (ct * 16 + lr) * 256;
#pragma unroll
            for (int c = 0; c < 4; ++c) {       // Khi slices (A-operand)
                const int g = c * 4 + hi8;
                const int slot = (g & 8) | ((g & 7) ^ kx);
                half8 kf = *(const half8*)&Ks[rowb + slot * 8];
                sacc[ct] = __builtin_amdgcn_mfma_f32_16x16x32_f16(kf, qf[c], sacc[ct], 0, 0, 0);
            }
#pragma unroll
            for (int c = 0; c < 4; ++c) {       // Klo slices
                const int g = c * 4 + hi8;
                const int slot = 16 | (g & 8) | ((g & 7) ^ kx);
                half8 kf = *(const half8*)&Ks[rowb + slot * 8];
                sacc[ct] = __builtin_amdgcn_mfma_f32_16x16x32_f16(kf, qf[c], sacc[ct], 0, 0, 0);
            }
        }

        // ---- in-register online softmax for q = lane&15 ----
        float tm;
        {
            float t0 = fmaxf(fmaxf(sacc[0][0], sacc[0][1]), fmaxf(sacc[0][2], sacc[0][3]));
            float t1 = fmaxf(fmaxf(sacc[1][0], sacc[1][1]), fmaxf(sacc[1][2], sacc[1][3]));
            float t2 = fmaxf(fmaxf(sacc[2][0], sacc[2][1]), fmaxf(sacc[2][2], sacc[2][3]));
            float t3 = fmaxf(fmaxf(sacc[3][0], sacc[3][1]), fmaxf(sacc[3][2], sacc[3][3]));
            tm = fmaxf(fmaxf(t0, t1), fmaxf(t2, t3));
        }
        tm = fmaxf(tm, __shfl_xor(tm, 16));
        tm = fmaxf(tm, __shfl_xor(tm, 32));
        const float mnew = fmaxf(mrun, tm);
        const float sc = __expf(mrun - mnew);
        float p[4][4];
        float ps = 0.f;
#pragma unroll
        for (int ct = 0; ct < 4; ++ct) {
            float s0 = __expf(sacc[ct][0] - mnew);
            float s1 = __expf(sacc[ct][1] - mnew);
            float s2 = __expf(sacc[ct][2] - mnew);
            float s3 = __expf(sacc[ct][3] - mnew);
            p[ct][0] = s0; p[ct][1] = s1; p[ct][2] = s2; p[ct][3] = s3;
            ps += (s0 + s1) + (s2 + s3);
        }
        ps += __shfl_xor(ps, 16);
        ps += __shfl_xor(ps, 32);
        lrun = lrun * sc + ps;
        mrun = mnew;

        // ---- packed P writes: 8 x b32 into [q][k] layout (pad 72) ----
#pragma unroll
        for (int ct = 0; ct < 4; ++ct) {
#pragma unroll
            for (int hh = 0; hh < 2; ++hh) {
                union { _Float16 h[2]; unsigned u; } pk;
                pk.h[0] = (_Float16)p[ct][2 * hh];
                pk.h[1] = (_Float16)p[ct][2 * hh + 1];
                *(unsigned*)&Pw[lr * 72 + ct * 16 + hi8 * 4 + 2 * hh] = pk.u;
            }
        }

        // ---- rescale acco (rows q = hi8*4+r): gather sc per row ----
        float sc4[4];
#pragma unroll
        for (int r = 0; r < 4; ++r) sc4[r] = __shfl(sc, hi8 * 4 + r);
#pragma unroll
        for (int dt = 0; dt < 8; ++dt)
#pragma unroll
            for (int r = 0; r < 4; ++r) acco[dt][r] *= sc4[r];

        // ---- PV (plain f16); P read layout unchanged ----
        half8 pf0 = *(const half8*)&Pw[lr * 72 + hi8 * 8];
        half8 pf1 = *(const half8*)&Pw[lr * 72 + 32 + hi8 * 8];
#pragma unroll
        for (int dt = 0; dt < 8; ++dt) {
            const int rowb = (dt * 16 + lr) * 64;
            half8 vf0 = *(const half8*)&Vs[rowb + ((0 + hi8) ^ kx) * 8];
            half8 vf1 = *(const half8*)&Vs[rowb + ((4 + hi8) ^ kx) * 8];
            acco[dt] = __builtin_amdgcn_mfma_f32_16x16x32_f16(pf0, vf0, acco[dt], 0, 0, 0);
            acco[dt] = __builtin_amdgcn_mfma_f32_16x16x32_f16(pf1, vf1, acco[dt], 0, 0, 0);
        }
        __syncthreads();   // all waves done reading before next stage overwrites
    }

    // epilogue: gather lrun per acco row, normalize, write f16 [S][2048]
    float inv4[4];
#pragma unroll
    for (int r = 0; r < 4; ++r) inv4[r] = 1.f / __shfl(lrun, hi8 * 4 + r);
#pragma unroll
    for (int dt = 0; dt < 8; ++dt) {
        const int n = h * 128 + dt * 16 + lr;
#pragma unroll
        for (int r = 0; r < 4; ++r) {
            const int srow = qt * 64 + w * 16 + hi8 * 4 + r;
            A2[(size_t)srow * 2048 + n] = (_Float16)(acco[dt][r] * inv4[r]);
        }
    }
}

// ---------------------------------------------------------------------------
// launch
// ---------------------------------------------------------------------------
extern "C" void kernel_launch(void* const* d_in, const int* in_sizes, int n_in,
                              void* d_out, int out_size, void* d_ws, size_t ws_size,
                              hipStream_t stream)
{
    const float* x    = (const float*)d_in[0];
    const float* Wqkv = (const float*)d_in[1];
    const float* bqkv = (const float*)d_in[2];
    const float* Wo   = (const float*)d_in[3];
    const float* bo   = (const float*)d_in[4];
    const int*   pid  = (const int*)d_in[5];
    float* out = (float*)d_out;
    char* ws = (char*)d_ws;

    // workspace layout (byte offsets, peak 112 MB):
    //  [0,8M)    xh (f16 hi) ..... then Wo2t [0,16M) (after GEMM1)
    //  [16M,64M) Wq2t ............ then Q2 [16,24) K2 [32,48) Vt [48,56) A2 [56,64)
    //  [64M,112M) qkv fp32 ....... dead after rope+tv
    const size_t MB = 1u << 20;
    _Float16* xh   = (_Float16*)(ws);
    _Float16* Wq2t = (_Float16*)(ws + 16 * MB);
    float*    qkv  = (float*)(ws + 64 * MB);
    _Float16* Q2   = (_Float16*)(ws + 16 * MB);
    _Float16* K2   = (_Float16*)(ws + 32 * MB);
    _Float16* Vtb  = (_Float16*)(ws + 48 * MB);
    _Float16* Wo2t = (_Float16*)(ws);
    _Float16* A2   = (_Float16*)(ws + 56 * MB);

    conv_x_kernel<<<2048, 256, 0, stream>>>(x, xh);
    tw_kernel<<<dim3(96, 32), 256, 0, stream>>>(Wqkv, Wq2t, 6144);
    // QKV projection: 2-term for Q/K columns (bx<32), 1-term for V
    gemm_split_kernel<<<768, 256, 0, stream>>>(xh, Wq2t, bqkv, qkv, 6144, 2048, 48, 768, 32, 2, 1);
    rope_kernel<<<2048, 256, 0, stream>>>(qkv, pid, Q2, K2);
    tv_kernel<<<dim3(32, 32), 256, 0, stream>>>(qkv, Vtb);
    tw_kernel<<<dim3(32, 32), 256, 0, stream>>>(Wo, Wo2t, 2048);

    // flash attention: 512 blocks (16h x 32 q-tiles), 2 blocks/CU
    attn_kernel<<<512, 256, 0, stream>>>(Q2, K2, Vtb, A2);

    // output projection: 2-term (Ah*Bh + Ah*Bl)
    gemm_split_kernel<<<256, 256, 0, stream>>>(A2, Wo2t, bo, out, 2048, 2048, 16, 256, 16, 2, 2);
}